// Round 8
// baseline (372.562 us; speedup 1.0000x reference)
//
#include <hip/hip_runtime.h>
#include <math.h>

#define RDIM 8192   // B*S
#define DDIM 1024   // 2*L
#define NDIM 8192
#define LDIM 512
#define KT 16       // K-tiles of 64 over K=1024

#define OFF_REAL 0
#define OFF_IMAG 4194304
#define OFF_SAL  8388608
#define OFF_CONF 8396800
#define OFF_LOSS 8404992
#define OFF_IDX  8404993

#define MAXCAND 128
#define MARGIN_Q 76        // 1.1875 units of d: 0.8 bias range + bf16 pair err + quant
#define QSCALE 64.0f
#define FLT_BIG 3.4e38f

typedef __attribute__((ext_vector_type(8))) short bf16x8;
typedef __attribute__((ext_vector_type(4))) float f32x4;

__device__ __forceinline__ unsigned short f2bf(float x) {
  unsigned u = __builtin_bit_cast(unsigned, x);
  unsigned r = (u + 0x7fff + ((u >> 16) & 1)) >> 16;
  return (unsigned short)r;
}

__device__ __forceinline__ void load_lds16(const void* g, void* l) {
  __builtin_amdgcn_global_load_lds((const __attribute__((address_space(1))) void*)g,
                                   (__attribute__((address_space(3))) void*)l, 16, 0, 0);
}

// quantize to biased int in [1, 65535]
__device__ __forceinline__ int qbias(float s) {
  int qi = __float2int_rn(s * QSCALE);
  qi = qi > 32767 ? 32767 : (qi < -32767 ? -32767 : qi);
  return qi + 32768;
}

// ============ bf16 cast + exact fp32 norms ============
__global__ __launch_bounds__(256)
void split_norms_kernel(const float* __restrict__ gw_real, const float* __restrict__ gw_imag,
                        const float* __restrict__ codebook,
                        unsigned short* __restrict__ zh, unsigned short* __restrict__ ch,
                        float* __restrict__ znorm, float* __restrict__ cnorm) {
  const int id = blockIdx.x;   // [0, 16384)
  const int t = threadIdx.x;   // 256
  float4 v;
  unsigned short* dst;
  if (id < RDIM) {
    v = (t < 128) ? reinterpret_cast<const float4*>(gw_real + (size_t)id * LDIM)[t]
                  : reinterpret_cast<const float4*>(gw_imag + (size_t)id * LDIM)[t - 128];
    dst = zh;
  } else {
    v = reinterpret_cast<const float4*>(codebook + (size_t)(id - RDIM) * DDIM)[t];
    dst = ch;
  }
  const size_t off = (size_t)(id < RDIM ? id : id - RDIM) * DDIM + t * 4;
  *reinterpret_cast<ushort4*>(dst + off) =
      make_ushort4(f2bf(v.x), f2bf(v.y), f2bf(v.z), f2bf(v.w));
  float s = v.x*v.x + v.y*v.y + v.z*v.z + v.w*v.w;
  __shared__ float red[256];
  red[t] = s;
  __syncthreads();
  for (int st = 128; st > 0; st >>= 1) {
    if (t < st) red[t] += red[t + st];
    __syncthreads();
  }
  if (t == 0) {
    if (id < RDIM) znorm[id] = red[0];
    else           cnorm[id - RDIM] = red[0];
  }
}

// ============ 256x256 tile, BK=64, 8-wave 4-phase bf16 GEMM ============
// Epilogue: per-row block-local min key (atomicMin to gkey) + candidates within
// blockmin+MARGIN_Q pushed to gcand (superset of global candidates; no q matrix).
#define STAGE(basep, kt, ldsbyte) do {                                        \
    load_lds16((basep) + eo1 + (kt) * 64, L + (ldsbyte) + wid * 1024);        \
    load_lds16((basep) + eo2 + (kt) * 64, L + (ldsbyte) + 8192 + wid * 1024); \
  } while (0)

__global__ __launch_bounds__(512)
void dist_mfma_kernel(const unsigned short* __restrict__ zh, const unsigned short* __restrict__ ch,
                      const float* __restrict__ cnorm,
                      unsigned* __restrict__ gkey, int* __restrict__ gcnt,
                      unsigned* __restrict__ gcand) {
  __shared__ unsigned short ldsbuf[65536];   // 128 KB: [buf][A 32K | B 32K]
  __shared__ unsigned skey[256][4];          // per-row per-wn wave min keys
  __shared__ int sthr[256];                  // per-row biased-q threshold
  char* const L = (char*)ldsbuf;

  // XCD-aware swizzle (1024 blocks = 8 XCDs x 128, bijective)
  const int sidx = (int)blockIdx.x;
  const int sw = (sidx & 7) * 128 + (sidx >> 3);
  const int bm = sw >> 5, bn = sw & 31;
  const int row0 = bm * 256, col0 = bn * 256;

  const int tid = threadIdx.x;
  const int wid = tid >> 6, l = tid & 63;
  const int wm = wid >> 2, wn = wid & 3;       // 2 x 4 wave grid
  const int lr = l & 15, lg = l >> 4;

  // ---- staging geometry: half-tile = 128 rows x 64 cols bf16 = 1024 chunks of 16B
  const int p1 = tid, p2 = tid + 512;
  const int r1 = p1 >> 3, c1 = (p1 & 7) ^ (r1 & 7);
  const int r2 = p2 >> 3, c2 = (p2 & 7) ^ (r2 & 7);
  const int eo1 = r1 * DDIM + c1 * 8;
  const int eo2 = r2 * DDIM + c2 * 8;
  const unsigned short* const az0 = zh + (size_t)row0 * DDIM;
  const unsigned short* const az1 = zh + (size_t)(row0 + 128) * DDIM;
  const unsigned short* const ac0 = ch + (size_t)col0 * DDIM;
  const unsigned short* const ac1 = ch + (size_t)(col0 + 128) * DDIM;

  // ---- fragment read offsets (row = base + lr, chunk' = (kh*4+lg) ^ (lr&7))
  const int fo0 = lr * 128 + ((lg ^ (lr & 7)) << 4);
  const int fo1 = fo0 ^ 64;

  f32x4 acc[4][8];
#pragma unroll
  for (int i = 0; i < 4; ++i)
#pragma unroll
    for (int j = 0; j < 8; ++j)
      acc[i][j] = (f32x4){0.f, 0.f, 0.f, 0.f};

  bf16x8 cfA[2][2], cfB[2][2], zf[4][2];

  // ---- prologue: tile0 (A+B) into buf0, B(1) into buf1; A(1) staged inside loop t=0
  STAGE(az0, 0, 0);
  STAGE(az1, 0, 16384);
  STAGE(ac0, 0, 32768);
  STAGE(ac1, 0, 49152);
  STAGE(ac0, 1, 98304);
  STAGE(ac1, 1, 114688);
  asm volatile("s_waitcnt vmcnt(4)" ::: "memory");   // tile0 landed; B(1) may fly
  __builtin_amdgcn_sched_barrier(0);
  __builtin_amdgcn_s_barrier();

  for (int t = 0; t < KT; ++t) {
    const int buf = t & 1, nbuf = buf ^ 1;
    const char* const Ab = L + buf * 65536 + wm * 16384;          // wave's z-half
    const char* const Bb = L + buf * 65536 + 32768 + wn * 8192;   // wave's c-64-block

    // ======== P1: quadrant (mf 0-1, nf 0-3); stage A0(t+1) ========
#pragma unroll
    for (int i = 0; i < 2; ++i) {
      cfA[i][0] = *reinterpret_cast<const bf16x8*>(Bb + i * 2048 + fo0);
      cfA[i][1] = *reinterpret_cast<const bf16x8*>(Bb + i * 2048 + fo1);
    }
#pragma unroll
    for (int j = 0; j < 4; ++j) {
      zf[j][0] = *reinterpret_cast<const bf16x8*>(Ab + j * 2048 + fo0);
      zf[j][1] = *reinterpret_cast<const bf16x8*>(Ab + j * 2048 + fo1);
    }
    if (t + 1 < KT) STAGE(az0, t + 1, nbuf * 65536);
    __builtin_amdgcn_sched_barrier(0);
    __builtin_amdgcn_s_barrier();
    __builtin_amdgcn_s_setprio(1);
#pragma unroll
    for (int kh = 0; kh < 2; ++kh)
#pragma unroll
      for (int i = 0; i < 2; ++i)
#pragma unroll
        for (int j = 0; j < 4; ++j)
          acc[i][j] = __builtin_amdgcn_mfma_f32_16x16x32_bf16(cfA[i][kh], zf[j][kh], acc[i][j], 0, 0, 0);
    __builtin_amdgcn_s_setprio(0);
    __builtin_amdgcn_sched_barrier(0);
    __builtin_amdgcn_s_barrier();

    // ======== P2: quadrant (mf 2-3, nf 0-3); stage A1(t+1) ========
#pragma unroll
    for (int i = 0; i < 2; ++i) {
      cfB[i][0] = *reinterpret_cast<const bf16x8*>(Bb + (2 + i) * 2048 + fo0);
      cfB[i][1] = *reinterpret_cast<const bf16x8*>(Bb + (2 + i) * 2048 + fo1);
    }
    if (t + 1 < KT) STAGE(az1, t + 1, nbuf * 65536 + 16384);
    __builtin_amdgcn_sched_barrier(0);
    __builtin_amdgcn_s_barrier();
    __builtin_amdgcn_s_setprio(1);
#pragma unroll
    for (int kh = 0; kh < 2; ++kh)
#pragma unroll
      for (int i = 0; i < 2; ++i)
#pragma unroll
        for (int j = 0; j < 4; ++j)
          acc[2 + i][j] = __builtin_amdgcn_mfma_f32_16x16x32_bf16(cfB[i][kh], zf[j][kh], acc[2 + i][j], 0, 0, 0);
    __builtin_amdgcn_s_setprio(0);
    __builtin_amdgcn_sched_barrier(0);
    __builtin_amdgcn_s_barrier();

    // ======== P3: quadrant (mf 2-3, nf 4-7); stage B0(t+2) into current buf ========
#pragma unroll
    for (int j = 0; j < 4; ++j) {
      zf[j][0] = *reinterpret_cast<const bf16x8*>(Ab + (4 + j) * 2048 + fo0);
      zf[j][1] = *reinterpret_cast<const bf16x8*>(Ab + (4 + j) * 2048 + fo1);
    }
    if (t + 2 < KT) STAGE(ac0, t + 2, buf * 65536 + 32768);
    __builtin_amdgcn_sched_barrier(0);
    __builtin_amdgcn_s_barrier();
    __builtin_amdgcn_s_setprio(1);
#pragma unroll
    for (int kh = 0; kh < 2; ++kh)
#pragma unroll
      for (int i = 0; i < 2; ++i)
#pragma unroll
        for (int j = 0; j < 4; ++j)
          acc[2 + i][4 + j] = __builtin_amdgcn_mfma_f32_16x16x32_bf16(cfB[i][kh], zf[j][kh], acc[2 + i][4 + j], 0, 0, 0);
    __builtin_amdgcn_s_setprio(0);
    __builtin_amdgcn_sched_barrier(0);
    __builtin_amdgcn_s_barrier();

    // ======== P4: quadrant (mf 0-1, nf 4-7); stage B1(t+2); counted vmcnt ========
    if (t + 2 < KT) STAGE(ac1, t + 2, buf * 65536 + 49152);
    if (t < KT - 2) { asm volatile("s_waitcnt vmcnt(4)" ::: "memory"); }
    else            { asm volatile("s_waitcnt vmcnt(0)" ::: "memory"); }
    __builtin_amdgcn_sched_barrier(0);
    __builtin_amdgcn_s_barrier();
    __builtin_amdgcn_s_setprio(1);
#pragma unroll
    for (int kh = 0; kh < 2; ++kh)
#pragma unroll
      for (int i = 0; i < 2; ++i)
#pragma unroll
        for (int j = 0; j < 4; ++j)
          acc[i][4 + j] = __builtin_amdgcn_mfma_f32_16x16x32_bf16(cfA[i][kh], zf[j][kh], acc[i][4 + j], 0, 0, 0);
    __builtin_amdgcn_s_setprio(0);
    __builtin_amdgcn_sched_barrier(0);
    __builtin_amdgcn_s_barrier();
  }

  // ---- epilogue pass 1: per-row min keys (no q matrix) ----
  const int czero = col0 + wn * 64;
  float cnv[4][4];
#pragma unroll
  for (int i = 0; i < 4; ++i) {
    const float4 c4 = *reinterpret_cast<const float4*>(cnorm + czero + i * 16 + lg * 4);
    cnv[i][0] = c4.x; cnv[i][1] = c4.y; cnv[i][2] = c4.z; cnv[i][3] = c4.w;
  }
#pragma unroll
  for (int j = 0; j < 8; ++j) {
    unsigned kmin = 0xffffffffu;
#pragma unroll
    for (int i = 0; i < 4; ++i)
#pragma unroll
      for (int reg = 0; reg < 4; ++reg) {
        const int qb = qbias(cnv[i][reg] - 2.0f * acc[i][j][reg]);
        const unsigned key = ((unsigned)qb << 13) | (unsigned)(czero + i * 16 + lg * 4 + reg);
        kmin = key < kmin ? key : kmin;
      }
    {  // reduce across the 4 lg lanes holding this row
      unsigned o = (unsigned)__shfl_xor((int)kmin, 16, 64);
      kmin = o < kmin ? o : kmin;
      o = (unsigned)__shfl_xor((int)kmin, 32, 64);
      kmin = o < kmin ? o : kmin;
    }
    if (lg == 0) skey[wm * 128 + j * 16 + lr][wn] = kmin;
  }
  __syncthreads();
  if (tid < 256) {
    unsigned m = skey[tid][0];
    m = skey[tid][1] < m ? skey[tid][1] : m;
    m = skey[tid][2] < m ? skey[tid][2] : m;
    m = skey[tid][3] < m ? skey[tid][3] : m;
    atomicMin(&gkey[row0 + tid], m);
    sthr[tid] = (int)(m >> 13) + MARGIN_Q;
  }
  __syncthreads();
  // ---- epilogue pass 2: push candidates within blockmin+MARGIN (superset of global set)
#pragma unroll
  for (int j = 0; j < 8; ++j) {
    const int rloc = wm * 128 + j * 16 + lr;
    const int thr = sthr[rloc];
    const int zr = row0 + rloc;
#pragma unroll
    for (int i = 0; i < 4; ++i)
#pragma unroll
      for (int reg = 0; reg < 4; ++reg) {
        const int qb = qbias(cnv[i][reg] - 2.0f * acc[i][j][reg]);
        if (qb <= thr) {
          const int pos = atomicAdd(&gcnt[zr], 1);
          if (pos < MAXCAND)
            gcand[(size_t)zr * MAXCAND + pos] =
                ((unsigned)qb << 13) | (unsigned)(czero + i * 16 + lg * 4 + reg);
        }
      }
  }
}

// ============ fused select (global filter) + exact fp32 refine ============
__global__ __launch_bounds__(64)
void select_refine_kernel(const float* __restrict__ gw_real, const float* __restrict__ gw_imag,
                          const float* __restrict__ codebook, const int* __restrict__ prev,
                          const float* __restrict__ adj, const float* __restrict__ znorm,
                          const float* __restrict__ cnorm,
                          const unsigned* __restrict__ gkey, const int* __restrict__ gcnt,
                          const unsigned* __restrict__ gcand,
                          float* __restrict__ out, float* __restrict__ minfinal,
                          int* __restrict__ idxfinal) {
  __shared__ int fcol[MAXCAND];
  __shared__ int fcnt_s;
  const int row = blockIdx.x;
  const int t = threadIdx.x;   // 64
  const unsigned gk = gkey[row];
  const int qmin_b = (int)(gk >> 13);
  const int winner = (int)(gk & 8191u);
  const int thr = qmin_b + MARGIN_Q;
  int cnt = gcnt[row];
  cnt = cnt > MAXCAND ? MAXCAND : cnt;
  if (t == 0) fcnt_s = 0;
  __syncthreads();
  for (int b = t; b < cnt; b += 64) {
    const unsigned e = gcand[(size_t)row * MAXCAND + b];
    if ((int)(e >> 13) <= thr) {
      const int p = atomicAdd(&fcnt_s, 1);
      fcol[p] = (int)(e & 8191u);
    }
  }
  __syncthreads();
  const int K = fcnt_s;
  if (K <= 1) {
    if (t == 0) {
      const int p = prev[row];
      const float bias = 0.8f / (1.0f + expf(-adj[(size_t)p * NDIM + winner]));
      out[OFF_IDX + row] = (float)winner;
      idxfinal[row] = winner;
      minfinal[row] = znorm[row] + (float)(qmin_b - 32768) * (1.0f / QSCALE) - bias;
    }
    return;
  }
  // exact fp32 over the K filtered candidates (lex-min on (d, idx))
  const int base = t * 16;
  const float* zp = (base < LDIM) ? gw_real + (size_t)row * LDIM + base
                                  : gw_imag + (size_t)row * LDIM + (base - LDIM);
  float z[16];
#pragma unroll
  for (int c = 0; c < 4; ++c) {
    const float4 v = reinterpret_cast<const float4*>(zp)[c];
    z[c*4+0] = v.x; z[c*4+1] = v.y; z[c*4+2] = v.z; z[c*4+3] = v.w;
  }
  const float zn = znorm[row];
  const int p = prev[row];
  float bestd = FLT_BIG;
  int besti = 0x7fffffff;
  for (int j = 0; j < K; ++j) {
    const int idx = fcol[j];
    const float* cp = codebook + (size_t)idx * DDIM + base;
    float dot = 0.f;
#pragma unroll
    for (int c = 0; c < 4; ++c) {
      const float4 v = reinterpret_cast<const float4*>(cp)[c];
      dot += z[c*4+0]*v.x + z[c*4+1]*v.y + z[c*4+2]*v.z + z[c*4+3]*v.w;
    }
    for (int m = 1; m < 64; m <<= 1) dot += __shfl_xor(dot, m, 64);
    const float d = zn + cnorm[idx] - 2.0f * dot
                  - 0.8f / (1.0f + expf(-adj[(size_t)p * NDIM + idx]));
    if (d < bestd || (d == bestd && idx < besti)) { bestd = d; besti = idx; }
  }
  if (t == 0) {
    out[OFF_IDX + row] = (float)besti;
    minfinal[row] = bestd;
    idxfinal[row] = besti;
  }
}

// ============ SHARED EPILOGUE ============

__global__ __launch_bounds__(256)
void epilogue_kernel(const float* __restrict__ gw_real, const float* __restrict__ gw_imag,
                     const float* __restrict__ codebook,
                     const float* __restrict__ sal_w, const float* __restrict__ sal_b,
                     const float* __restrict__ conf_w, const float* __restrict__ conf_b,
                     const float* __restrict__ minfinal, const int* __restrict__ idxfinal,
                     float* __restrict__ out, float* __restrict__ rowloss) {
  const int row = blockIdx.x;
  const int t = threadIdx.x;
  const int k = t << 2;
  const int idx = idxfinal[row];
  const float4 qv = *reinterpret_cast<const float4*>(codebook + (size_t)idx * DDIM + k);
  float4 z;
  if (k < LDIM) z = *reinterpret_cast<const float4*>(gw_real + (size_t)row * LDIM + k);
  else          z = *reinterpret_cast<const float4*>(gw_imag + (size_t)row * LDIM + (k - LDIM));
  const float dx = qv.x - z.x, dy = qv.y - z.y, dz = qv.z - z.z, dw = qv.w - z.w;
  float4 st;
  st.x = z.x + dx; st.y = z.y + dy; st.z = z.z + dz; st.w = z.w + dw;
  float* dst = (k < LDIM) ? (out + OFF_REAL + (size_t)row * LDIM + k)
                          : (out + OFF_IMAG + (size_t)row * LDIM + (k - LDIM));
  *reinterpret_cast<float4*>(dst) = st;
  const float4 sw = *reinterpret_cast<const float4*>(sal_w + k);
  const float4 cw = *reinterpret_cast<const float4*>(conf_w + k);
  const float sdot = st.x*sw.x + st.y*sw.y + st.z*sw.z + st.w*sw.w;
  const float cdot = st.x*cw.x + st.y*cw.y + st.z*cw.z + st.w*cw.w;
  const float dif = dx*dx + dy*dy + dz*dz + dw*dw;
  __shared__ float r1[256], r2[256], r3[256];
  r1[t] = sdot; r2[t] = cdot; r3[t] = dif;
  __syncthreads();
  for (int s = 128; s > 0; s >>= 1) {
    if (t < s) { r1[t] += r1[t + s]; r2[t] += r2[t + s]; r3[t] += r3[t + s]; }
    __syncthreads();
  }
  if (t == 0) {
    out[OFF_SAL + row]  = r1[0] + sal_b[0] + 0.1f * (-minfinal[row]);
    out[OFF_CONF + row] = 1.0f / (1.0f + expf(-(r2[0] + conf_b[0])));
    rowloss[row] = r3[0];
  }
}

__global__ __launch_bounds__(256)
void loss_kernel(const float* __restrict__ rowloss, float* __restrict__ out) {
  const int t = threadIdx.x;
  float s = 0.f;
  for (int i = t; i < RDIM; i += 256) s += rowloss[i];
  __shared__ float red[256];
  red[t] = s;
  __syncthreads();
  for (int st = 128; st > 0; st >>= 1) {
    if (t < st) red[t] += red[t + st];
    __syncthreads();
  }
  if (t == 0) {
    const float m = red[0] / (float)((size_t)RDIM * DDIM);
    out[OFF_LOSS] = m + 0.01f * m;
  }
}

// ============ FALLBACK (round-1 fp32 path) ============

__global__ __launch_bounds__(256)
void norms_kernel(const float* __restrict__ gw_real, const float* __restrict__ gw_imag,
                  const float* __restrict__ codebook,
                  float* __restrict__ znorm, float* __restrict__ cnorm) {
  const int id = blockIdx.x;
  const int t = threadIdx.x;
  float s;
  if (id < RDIM) {
    const float4* zr = reinterpret_cast<const float4*>(gw_real + (size_t)id * LDIM);
    const float4* zi = reinterpret_cast<const float4*>(gw_imag + (size_t)id * LDIM);
    const float4 v = (t < 128) ? zr[t] : zi[t - 128];
    s = v.x*v.x + v.y*v.y + v.z*v.z + v.w*v.w;
  } else {
    const float4* c = reinterpret_cast<const float4*>(codebook + (size_t)(id - RDIM) * DDIM);
    const float4 v = c[t];
    s = v.x*v.x + v.y*v.y + v.z*v.z + v.w*v.w;
  }
  __shared__ float red[256];
  red[t] = s;
  __syncthreads();
  for (int st = 128; st > 0; st >>= 1) {
    if (t < st) red[t] += red[t + st];
    __syncthreads();
  }
  if (t == 0) {
    if (id < RDIM) znorm[id] = red[0];
    else           cnorm[id - RDIM] = red[0];
  }
}

__global__ __launch_bounds__(256)
void dist_kernel(const float* __restrict__ gw_real, const float* __restrict__ gw_imag,
                 const float* __restrict__ codebook, const int* __restrict__ prev,
                 const float* __restrict__ adj, const float* __restrict__ znorm,
                 const float* __restrict__ cnorm,
                 float* __restrict__ ws_min, int* __restrict__ ws_idx) {
  __shared__ float As[16][64];
  __shared__ float Bs[16][64];
  __shared__ int prevs[64];
  const int bm = blockIdx.x, bn = blockIdx.y;
  const int row0 = bm * 64, col0 = bn * 64;
  const int tid = threadIdx.x;
  const int tx = tid & 15, ty = tid >> 4;
  if (tid < 64) prevs[tid] = prev[row0 + tid];
  const int lm = tid >> 2;
  const int lk = (tid & 3) << 2;
  const int arow = row0 + lm;
  const int brow = col0 + lm;
  float acc[4][4] = {{0.f,0.f,0.f,0.f},{0.f,0.f,0.f,0.f},{0.f,0.f,0.f,0.f},{0.f,0.f,0.f,0.f}};
  for (int kk = 0; kk < DDIM; kk += 16) {
    const int k = kk + lk;
    float4 a, b;
    if (k < LDIM) a = *reinterpret_cast<const float4*>(gw_real + (size_t)arow * LDIM + k);
    else          a = *reinterpret_cast<const float4*>(gw_imag + (size_t)arow * LDIM + (k - LDIM));
    b = *reinterpret_cast<const float4*>(codebook + (size_t)brow * DDIM + k);
    __syncthreads();
    As[lk+0][lm]=a.x; As[lk+1][lm]=a.y; As[lk+2][lm]=a.z; As[lk+3][lm]=a.w;
    Bs[lk+0][lm]=b.x; Bs[lk+1][lm]=b.y; Bs[lk+2][lm]=b.z; Bs[lk+3][lm]=b.w;
    __syncthreads();
#pragma unroll
    for (int k2 = 0; k2 < 16; ++k2) {
      const float4 a4 = *reinterpret_cast<const float4*>(&As[k2][ty << 2]);
      const float4 b4 = *reinterpret_cast<const float4*>(&Bs[k2][tx << 2]);
      const float av[4] = {a4.x, a4.y, a4.z, a4.w};
      const float bv[4] = {b4.x, b4.y, b4.z, b4.w};
#pragma unroll
      for (int i = 0; i < 4; ++i)
#pragma unroll
        for (int j = 0; j < 4; ++j)
          acc[i][j] = fmaf(av[i], bv[j], acc[i][j]);
    }
  }
  const float4 cn4 = *reinterpret_cast<const float4*>(cnorm + col0 + (tx << 2));
  const float cnv[4] = {cn4.x, cn4.y, cn4.z, cn4.w};
#pragma unroll
  for (int i = 0; i < 4; ++i) {
    const int rsub = (ty << 2) + i;
    const int row = row0 + rsub;
    const float zn = znorm[row];
    const int p = prevs[rsub];
    const float4 ad4 = *reinterpret_cast<const float4*>(adj + (size_t)p * NDIM + col0 + (tx << 2));
    const float adv[4] = {ad4.x, ad4.y, ad4.z, ad4.w};
    float bv = FLT_BIG;
    int bi = -1;
#pragma unroll
    for (int j = 0; j < 4; ++j) {
      const float bias = 0.8f * (1.0f / (1.0f + expf(-adv[j])));
      const float dv = (zn + cnv[j]) - 2.0f * acc[i][j] - bias;
      const int col = col0 + (tx << 2) + j;
      if (dv < bv) { bv = dv; bi = col; }
    }
    for (int m = 1; m < 16; m <<= 1) {
      const float ov = __shfl_xor(bv, m, 64);
      const int   oi = __shfl_xor(bi, m, 64);
      if (ov < bv || (ov == bv && oi < bi)) { bv = ov; bi = oi; }
    }
    if (tx == 0) {
      ws_min[(size_t)row * 128 + bn] = bv;
      ws_idx[(size_t)row * 128 + bn] = bi;
    }
  }
}

__global__ __launch_bounds__(128)
void argmin_reduce(const float* __restrict__ ws_min, const int* __restrict__ ws_idx,
                   float* __restrict__ out, float* __restrict__ minfinal,
                   int* __restrict__ idxfinal) {
  const int row = blockIdx.x;
  const int t = threadIdx.x;
  __shared__ float sv[128];
  __shared__ int   si[128];
  sv[t] = ws_min[(size_t)row * 128 + t];
  si[t] = ws_idx[(size_t)row * 128 + t];
  __syncthreads();
  for (int s = 64; s > 0; s >>= 1) {
    if (t < s) {
      const float ov = sv[t + s];
      const int   oi = si[t + s];
      if (ov < sv[t] || (ov == sv[t] && oi < si[t])) { sv[t] = ov; si[t] = oi; }
    }
    __syncthreads();
  }
  if (t == 0) {
    out[OFF_IDX + row] = (float)si[0];
    minfinal[row] = sv[0];
    idxfinal[row] = si[0];
  }
}

// ============ HOST ============

extern "C" void kernel_launch(void* const* d_in, const int* in_sizes, int n_in,
                              void* d_out, int out_size, void* d_ws, size_t ws_size,
                              hipStream_t stream) {
  const float* gw_real  = (const float*)d_in[0];
  const float* gw_imag  = (const float*)d_in[1];
  const int*   prev     = (const int*)d_in[2];
  const float* codebook = (const float*)d_in[3];
  const float* adj      = (const float*)d_in[4];
  const float* sal_w    = (const float*)d_in[5];
  const float* sal_b    = (const float*)d_in[6];
  const float* conf_w   = (const float*)d_in[7];
  const float* conf_b   = (const float*)d_in[8];
  float* out = (float*)d_out;
  char* ws = (char*)d_ws;

  const size_t matsz = (size_t)RDIM * DDIM;              // bf16 elements per matrix
  size_t need = 2 * matsz * 2                            // zh, ch (bf16)
              + (size_t)RDIM * 4 * 2                     // gkey, gcnt
              + (size_t)RDIM * MAXCAND * 4               // gcand
              + 5 * (size_t)RDIM * 4 + 4096;             // znorm,cnorm,minfinal,idxfinal,rowloss

  if (ws_size >= need) {
    unsigned short* zh = (unsigned short*)ws;
    unsigned short* chh = zh + matsz;
    unsigned* gkey  = (unsigned*)(chh + matsz);
    int*      gcnt  = (int*)(gkey + RDIM);
    unsigned* gcand = (unsigned*)(gcnt + RDIM);
    float* znorm    = (float*)(gcand + (size_t)RDIM * MAXCAND);
    float* cnorm    = znorm + RDIM;
    float* minfinal = cnorm + NDIM;
    int*   idxfinal = (int*)(minfinal + RDIM);
    float* rowloss  = (float*)(idxfinal + RDIM);

    hipMemsetAsync(gkey, 0xFF, (size_t)RDIM * 4, stream);   // keys to UINT_MAX
    hipMemsetAsync(gcnt, 0, (size_t)RDIM * 4, stream);
    split_norms_kernel<<<RDIM + NDIM, 256, 0, stream>>>(gw_real, gw_imag, codebook,
                                                        zh, chh, znorm, cnorm);
    dist_mfma_kernel<<<1024, 512, 0, stream>>>(zh, chh, cnorm, gkey, gcnt, gcand);
    select_refine_kernel<<<RDIM, 64, 0, stream>>>(gw_real, gw_imag, codebook, prev, adj,
                                                  znorm, cnorm, gkey, gcnt, gcand,
                                                  out, minfinal, idxfinal);
    epilogue_kernel<<<RDIM, 256, 0, stream>>>(gw_real, gw_imag, codebook, sal_w, sal_b,
                                              conf_w, conf_b, minfinal, idxfinal, out, rowloss);
    loss_kernel<<<1, 256, 0, stream>>>(rowloss, out);
  } else {
    float* ws_min   = (float*)ws;
    int*   ws_idx   = (int*)(ws + (size_t)RDIM * 128 * 4);
    float* znorm    = (float*)(ws + (size_t)RDIM * 128 * 8);
    float* cnorm    = znorm + RDIM;
    float* minfinal = cnorm + NDIM;
    int*   idxfinal = (int*)(minfinal + RDIM);
    float* rowloss  = (float*)(idxfinal + RDIM);

    norms_kernel<<<RDIM + NDIM, 256, 0, stream>>>(gw_real, gw_imag, codebook, znorm, cnorm);
    dist_kernel<<<dim3(RDIM / 64, NDIM / 64), 256, 0, stream>>>(
        gw_real, gw_imag, codebook, prev, adj, znorm, cnorm, ws_min, ws_idx);
    argmin_reduce<<<RDIM, 128, 0, stream>>>(ws_min, ws_idx, out, minfinal, idxfinal);
    epilogue_kernel<<<RDIM, 256, 0, stream>>>(gw_real, gw_imag, codebook, sal_w, sal_b,
                                              conf_w, conf_b, minfinal, idxfinal, out, rowloss);
    loss_kernel<<<1, 256, 0, stream>>>(rowloss, out);
  }
}

// Round 9
// 227.504 us; speedup vs baseline: 1.6376x; 1.6376x over previous
//
#include <hip/hip_runtime.h>
#include <math.h>

#define RDIM 8192   // B*S
#define DDIM 1024   // 2*L
#define NDIM 8192
#define LDIM 512
#define NKT 64      // 4 column-tiles x 16 K-steps of 64, linearized

#define OFF_REAL 0
#define OFF_IMAG 4194304
#define OFF_SAL  8388608
#define OFF_CONF 8396800
#define OFF_LOSS 8404992
#define OFF_IDX  8404993

#define MAXCAND 64
#define MARGIN_Q 76        // 1.1875 units of d: 0.8 bias range + bf16 pair err + quant
#define QSCALE 64.0f
#define FLT_BIG 3.4e38f

typedef __attribute__((ext_vector_type(8))) short bf16x8;
typedef __attribute__((ext_vector_type(8))) short short8v;
typedef __attribute__((ext_vector_type(4))) float f32x4;

__device__ __forceinline__ unsigned short f2bf(float x) {
  unsigned u = __builtin_bit_cast(unsigned, x);
  unsigned r = (u + 0x7fff + ((u >> 16) & 1)) >> 16;
  return (unsigned short)r;
}

__device__ __forceinline__ void load_lds16(const void* g, void* l) {
  __builtin_amdgcn_global_load_lds((const __attribute__((address_space(1))) void*)g,
                                   (__attribute__((address_space(3))) void*)l, 16, 0, 0);
}

__device__ __forceinline__ short clampq(float s) {
  int qi = __float2int_rn(s * QSCALE);
  qi = qi > 32767 ? 32767 : (qi < -32767 ? -32767 : qi);
  return (short)qi;
}

// ============ bf16 cast + exact fp32 norms ============
__global__ __launch_bounds__(256)
void split_norms_kernel(const float* __restrict__ gw_real, const float* __restrict__ gw_imag,
                        const float* __restrict__ codebook,
                        unsigned short* __restrict__ zh, unsigned short* __restrict__ ch,
                        float* __restrict__ znorm, float* __restrict__ cnorm) {
  const int id = blockIdx.x;   // [0, 16384)
  const int t = threadIdx.x;   // 256
  float4 v;
  unsigned short* dst;
  if (id < RDIM) {
    v = (t < 128) ? reinterpret_cast<const float4*>(gw_real + (size_t)id * LDIM)[t]
                  : reinterpret_cast<const float4*>(gw_imag + (size_t)id * LDIM)[t - 128];
    dst = zh;
  } else {
    v = reinterpret_cast<const float4*>(codebook + (size_t)(id - RDIM) * DDIM)[t];
    dst = ch;
  }
  const size_t off = (size_t)(id < RDIM ? id : id - RDIM) * DDIM + t * 4;
  *reinterpret_cast<ushort4*>(dst + off) =
      make_ushort4(f2bf(v.x), f2bf(v.y), f2bf(v.z), f2bf(v.w));
  float s = v.x*v.x + v.y*v.y + v.z*v.z + v.w*v.w;
  __shared__ float red[256];
  red[t] = s;
  __syncthreads();
  for (int st = 128; st > 0; st >>= 1) {
    if (t < st) red[t] += red[t + st];
    __syncthreads();
  }
  if (t == 0) {
    if (id < RDIM) znorm[id] = red[0];
    else           cnorm[id - RDIM] = red[0];
  }
}

// ============ persistent 256-row panel x 4 column tiles, BK=64, 8-wave 4-phase ============
#define STAGE(basep, koff, ldsbyte) do {                                        \
    load_lds16((basep) + eo1 + (koff) * 64, L + (ldsbyte) + wid * 1024);        \
    load_lds16((basep) + eo2 + (koff) * 64, L + (ldsbyte) + 8192 + wid * 1024); \
  } while (0)

__global__ __launch_bounds__(512)
void dist_mfma_kernel(const unsigned short* __restrict__ zh, const unsigned short* __restrict__ ch,
                      const float* __restrict__ cnorm, short* __restrict__ q) {
  __shared__ unsigned short ldsbuf[65536];   // 128 KB: [buf][A 32K | B 32K]
  char* const L = (char*)ldsbuf;

  // XCD swizzle (256 blocks = 8 XCDs x 32), bm-major: one XCD shares 4 z-panels
  const int sidx = (int)blockIdx.x;
  const int sw = (sidx & 7) * 32 + (sidx >> 3);
  const int bm = sw >> 3, bg = sw & 7;       // bm in [0,32), col-group bg in [0,8)
  const int row0 = bm * 256;

  const int tid = threadIdx.x;
  const int wid = tid >> 6, l = tid & 63;
  const int wm = wid >> 2, wn = wid & 3;       // 2 x 4 wave grid
  const int lr = l & 15, lg = l >> 4;

  // ---- staging geometry: half-tile = 128 rows x 64 cols bf16 = 1024 chunks of 16B
  const int p1 = tid, p2 = tid + 512;
  const int r1 = p1 >> 3, c1 = (p1 & 7) ^ (r1 & 7);
  const int r2 = p2 >> 3, c2 = (p2 & 7) ^ (r2 & 7);
  const int eo1 = r1 * DDIM + c1 * 8;
  const int eo2 = r2 * DDIM + c2 * 8;
  const unsigned short* const az0 = zh + (size_t)row0 * DDIM;
  const unsigned short* const az1 = zh + (size_t)(row0 + 128) * DDIM;

  // ---- fragment read offsets (row = base + lr, chunk' = (kh*4+lg) ^ (lr&7))
  const int fo0 = lr * 128 + ((lg ^ (lr & 7)) << 4);
  const int fo1 = fo0 ^ 64;

  f32x4 acc[4][8];
#pragma unroll
  for (int i = 0; i < 4; ++i)
#pragma unroll
    for (int j = 0; j < 8; ++j)
      acc[i][j] = (f32x4){0.f, 0.f, 0.f, 0.f};

  bf16x8 cfA[2][2], cfB[2][2], zf[4][2];

  // ---- prologue: A(k0)+B(kt0) into buf0, B(kt1) into buf1
  {
    const unsigned short* const b0 = ch + (size_t)(bg * 4 * 256) * DDIM;
    STAGE(az0, 0, 0);
    STAGE(az1, 0, 16384);
    STAGE(b0, 0, 32768);
    STAGE(b0 + (size_t)128 * DDIM, 0, 49152);
    STAGE(b0, 1, 98304);
    STAGE(b0 + (size_t)128 * DDIM, 1, 114688);
  }
  asm volatile("s_waitcnt vmcnt(4)" ::: "memory");
  __builtin_amdgcn_sched_barrier(0);
  __builtin_amdgcn_s_barrier();

  for (int t = 0; t < NKT; ++t) {
    const int buf = t & 1, nbuf = buf ^ 1;
    const char* const Ab = L + buf * 65536 + wm * 16384;          // wave's z-half
    const char* const Bb = L + buf * 65536 + 32768 + wn * 8192;   // wave's c-64-block
    const int kA = (t + 1) & 15;                                  // A wraps within panel
    const int bt = t + 2;                                         // B K-step (crosses panels)
    const unsigned short* const bc = ch + (size_t)((bg * 4 + (bt >> 4)) * 256) * DDIM;

    // ======== P1: quadrant (mf 0-1, nf 0-3); stage A0(t+1) ========
#pragma unroll
    for (int i = 0; i < 2; ++i) {
      cfA[i][0] = *reinterpret_cast<const bf16x8*>(Bb + i * 2048 + fo0);
      cfA[i][1] = *reinterpret_cast<const bf16x8*>(Bb + i * 2048 + fo1);
    }
#pragma unroll
    for (int j = 0; j < 4; ++j) {
      zf[j][0] = *reinterpret_cast<const bf16x8*>(Ab + j * 2048 + fo0);
      zf[j][1] = *reinterpret_cast<const bf16x8*>(Ab + j * 2048 + fo1);
    }
    if (t + 1 < NKT) STAGE(az0, kA, nbuf * 65536);
    __builtin_amdgcn_sched_barrier(0);
    __builtin_amdgcn_s_barrier();
    __builtin_amdgcn_s_setprio(1);
#pragma unroll
    for (int kh = 0; kh < 2; ++kh)
#pragma unroll
      for (int i = 0; i < 2; ++i)
#pragma unroll
        for (int j = 0; j < 4; ++j)
          acc[i][j] = __builtin_amdgcn_mfma_f32_16x16x32_bf16(cfA[i][kh], zf[j][kh], acc[i][j], 0, 0, 0);
    __builtin_amdgcn_s_setprio(0);
    __builtin_amdgcn_sched_barrier(0);
    __builtin_amdgcn_s_barrier();

    // ======== P2: quadrant (mf 2-3, nf 0-3); stage A1(t+1) ========
#pragma unroll
    for (int i = 0; i < 2; ++i) {
      cfB[i][0] = *reinterpret_cast<const bf16x8*>(Bb + (2 + i) * 2048 + fo0);
      cfB[i][1] = *reinterpret_cast<const bf16x8*>(Bb + (2 + i) * 2048 + fo1);
    }
    if (t + 1 < NKT) STAGE(az1, kA, nbuf * 65536 + 16384);
    __builtin_amdgcn_sched_barrier(0);
    __builtin_amdgcn_s_barrier();
    __builtin_amdgcn_s_setprio(1);
#pragma unroll
    for (int kh = 0; kh < 2; ++kh)
#pragma unroll
      for (int i = 0; i < 2; ++i)
#pragma unroll
        for (int j = 0; j < 4; ++j)
          acc[2 + i][j] = __builtin_amdgcn_mfma_f32_16x16x32_bf16(cfB[i][kh], zf[j][kh], acc[2 + i][j], 0, 0, 0);
    __builtin_amdgcn_s_setprio(0);
    __builtin_amdgcn_sched_barrier(0);
    __builtin_amdgcn_s_barrier();

    // ======== P3: quadrant (mf 2-3, nf 4-7); stage B0(t+2) into current buf ========
#pragma unroll
    for (int j = 0; j < 4; ++j) {
      zf[j][0] = *reinterpret_cast<const bf16x8*>(Ab + (4 + j) * 2048 + fo0);
      zf[j][1] = *reinterpret_cast<const bf16x8*>(Ab + (4 + j) * 2048 + fo1);
    }
    if (bt < NKT) STAGE(bc, bt & 15, buf * 65536 + 32768);
    __builtin_amdgcn_sched_barrier(0);
    __builtin_amdgcn_s_barrier();
    __builtin_amdgcn_s_setprio(1);
#pragma unroll
    for (int kh = 0; kh < 2; ++kh)
#pragma unroll
      for (int i = 0; i < 2; ++i)
#pragma unroll
        for (int j = 0; j < 4; ++j)
          acc[2 + i][4 + j] = __builtin_amdgcn_mfma_f32_16x16x32_bf16(cfB[i][kh], zf[j][kh], acc[2 + i][4 + j], 0, 0, 0);
    __builtin_amdgcn_s_setprio(0);
    __builtin_amdgcn_sched_barrier(0);
    __builtin_amdgcn_s_barrier();

    // ======== P4: quadrant (mf 0-1, nf 4-7); stage B1(t+2); counted vmcnt ========
    if (bt < NKT) STAGE(bc + (size_t)128 * DDIM, bt & 15, buf * 65536 + 49152);
    if (t < NKT - 2) { asm volatile("s_waitcnt vmcnt(4)" ::: "memory"); }
    else             { asm volatile("s_waitcnt vmcnt(0)" ::: "memory"); }
    __builtin_amdgcn_sched_barrier(0);
    __builtin_amdgcn_s_barrier();
    __builtin_amdgcn_s_setprio(1);
#pragma unroll
    for (int kh = 0; kh < 2; ++kh)
#pragma unroll
      for (int i = 0; i < 2; ++i)
#pragma unroll
        for (int j = 0; j < 4; ++j)
          acc[i][4 + j] = __builtin_amdgcn_mfma_f32_16x16x32_bf16(cfA[i][kh], zf[j][kh], acc[i][4 + j], 0, 0, 0);
    __builtin_amdgcn_s_setprio(0);
    __builtin_amdgcn_sched_barrier(0);
    __builtin_amdgcn_s_barrier();

    // ======== tile boundary: quantize+store this column tile, rezero acc ========
    // Stores overlap the already-in-flight B(t+1..t+2) staging of the next tile.
    if ((t & 15) == 15) {
      const int czero = (bg * 4 + (t >> 4)) * 256 + wn * 64;
      const int zzero = row0 + wm * 128;
#pragma unroll
      for (int i = 0; i < 4; ++i) {
        const int cc = czero + i * 16 + lg * 4;
        const float4 cn4 = *reinterpret_cast<const float4*>(cnorm + cc);
#pragma unroll
        for (int j = 0; j < 8; ++j) {
          const int zr = zzero + j * 16 + lr;
          const f32x4 a = acc[i][j];
          *reinterpret_cast<short4*>(q + (size_t)zr * NDIM + cc) =
              make_short4(clampq(cn4.x - 2.0f * a[0]), clampq(cn4.y - 2.0f * a[1]),
                          clampq(cn4.z - 2.0f * a[2]), clampq(cn4.w - 2.0f * a[3]));
          acc[i][j] = (f32x4){0.f, 0.f, 0.f, 0.f};
        }
      }
    }
  }
}

// ============ streaming per-row min + candidate collection ============
__global__ __launch_bounds__(256)
void collect_kernel(const short* __restrict__ q, const int* __restrict__ prev,
                    const float* __restrict__ adj, const float* __restrict__ znorm,
                    float* __restrict__ out, float* __restrict__ minfinal,
                    int* __restrict__ idxfinal,
                    int* __restrict__ gcount, int* __restrict__ gcand) {
  __shared__ unsigned s_wmin[4];
  __shared__ int s_cnt;
  __shared__ int s_list[MAXCAND];
  const int row = blockIdx.x;
  const int t = threadIdx.x;    // 256
  if (t == 0) s_cnt = 0;
  short8v v[4];
  unsigned kmin = 0xffffffffu;
#pragma unroll
  for (int c = 0; c < 4; ++c) {
    v[c] = *reinterpret_cast<const short8v*>(q + (size_t)row * NDIM + (c * 256 + t) * 8);
#pragma unroll
    for (int j = 0; j < 8; ++j) {
      const int col = (c * 256 + t) * 8 + j;
      const unsigned key = (((unsigned)((int)v[c][j] + 32768)) << 13) | (unsigned)col;
      kmin = (key < kmin) ? key : kmin;     // lex (q, col) min
    }
  }
  for (int m = 1; m < 64; m <<= 1) {
    const unsigned o = (unsigned)__shfl_xor((int)kmin, m, 64);
    kmin = (o < kmin) ? o : kmin;
  }
  if ((t & 63) == 0) s_wmin[t >> 6] = kmin;
  __syncthreads();
  unsigned gk = s_wmin[0];
  gk = gk < s_wmin[1] ? gk : s_wmin[1];
  gk = gk < s_wmin[2] ? gk : s_wmin[2];
  gk = gk < s_wmin[3] ? gk : s_wmin[3];
  const int qmin = (int)(gk >> 13) - 32768;
  const int winner = (int)(gk & 8191u);
  const int thr = qmin + MARGIN_Q;
#pragma unroll
  for (int c = 0; c < 4; ++c) {
#pragma unroll
    for (int j = 0; j < 8; ++j) {
      if ((int)v[c][j] <= thr) {
        const int pos = atomicAdd(&s_cnt, 1);
        if (pos < MAXCAND) s_list[pos] = (c * 256 + t) * 8 + j;
      }
    }
  }
  __syncthreads();
  const int cnt = (s_cnt < MAXCAND) ? s_cnt : MAXCAND;
  if (t == 0) {
    gcount[row] = (cnt <= 1) ? 1 : cnt;
    out[OFF_IDX + row] = (float)winner;
    idxfinal[row] = winner;
    if (cnt <= 1) {
      const int p = prev[row];
      const float bias = 0.8f / (1.0f + expf(-adj[(size_t)p * NDIM + winner]));
      minfinal[row] = znorm[row] + (float)qmin * (1.0f / QSCALE) - bias;
    } else {
      minfinal[row] = znorm[row] + (float)qmin * (1.0f / QSCALE);  // refine overwrites
    }
  }
  if (cnt > 1 && t < cnt) gcand[(size_t)row * MAXCAND + t] = s_list[t];
}

// ============ exact fp32 refine of ambiguous rows (biased lex-min over candidates) ============
__global__ __launch_bounds__(64)
void refine_kernel(const float* __restrict__ gw_real, const float* __restrict__ gw_imag,
                   const float* __restrict__ codebook, const int* __restrict__ prev,
                   const float* __restrict__ adj, const float* __restrict__ znorm,
                   const float* __restrict__ cnorm,
                   const int* __restrict__ gcount, const int* __restrict__ gcand,
                   float* __restrict__ out, float* __restrict__ minfinal,
                   int* __restrict__ idxfinal) {
  const int row = blockIdx.x;
  const int t = threadIdx.x;   // 64 lanes, 16 contiguous floats each
  const int K = gcount[row];
  if (K <= 1) return;
  const int base = t * 16;
  const float* zp = (base < LDIM) ? gw_real + (size_t)row * LDIM + base
                                  : gw_imag + (size_t)row * LDIM + (base - LDIM);
  float z[16];
#pragma unroll
  for (int c = 0; c < 4; ++c) {
    const float4 v = reinterpret_cast<const float4*>(zp)[c];
    z[c*4+0] = v.x; z[c*4+1] = v.y; z[c*4+2] = v.z; z[c*4+3] = v.w;
  }
  const float zn = znorm[row];
  const int p = prev[row];
  float bestd = FLT_BIG;
  int besti = 0x7fffffff;
  for (int j = 0; j < K; ++j) {
    const int idx = gcand[(size_t)row * MAXCAND + j];
    const float* cp = codebook + (size_t)idx * DDIM + base;
    float dot = 0.f;
#pragma unroll
    for (int c = 0; c < 4; ++c) {
      const float4 v = reinterpret_cast<const float4*>(cp)[c];
      dot += z[c*4+0]*v.x + z[c*4+1]*v.y + z[c*4+2]*v.z + z[c*4+3]*v.w;
    }
    for (int m = 1; m < 64; m <<= 1) dot += __shfl_xor(dot, m, 64);
    const float d = zn + cnorm[idx] - 2.0f * dot
                  - 0.8f / (1.0f + expf(-adj[(size_t)p * NDIM + idx]));
    if (d < bestd || (d == bestd && idx < besti)) { bestd = d; besti = idx; }
  }
  if (t == 0) {
    out[OFF_IDX + row] = (float)besti;
    minfinal[row] = bestd;
    idxfinal[row] = besti;
  }
}

// ============ SHARED EPILOGUE ============

__global__ __launch_bounds__(256)
void epilogue_kernel(const float* __restrict__ gw_real, const float* __restrict__ gw_imag,
                     const float* __restrict__ codebook,
                     const float* __restrict__ sal_w, const float* __restrict__ sal_b,
                     const float* __restrict__ conf_w, const float* __restrict__ conf_b,
                     const float* __restrict__ minfinal, const int* __restrict__ idxfinal,
                     float* __restrict__ out, float* __restrict__ rowloss) {
  const int row = blockIdx.x;
  const int t = threadIdx.x;
  const int k = t << 2;
  const int idx = idxfinal[row];
  const float4 qv = *reinterpret_cast<const float4*>(codebook + (size_t)idx * DDIM + k);
  float4 z;
  if (k < LDIM) z = *reinterpret_cast<const float4*>(gw_real + (size_t)row * LDIM + k);
  else          z = *reinterpret_cast<const float4*>(gw_imag + (size_t)row * LDIM + (k - LDIM));
  const float dx = qv.x - z.x, dy = qv.y - z.y, dz = qv.z - z.z, dw = qv.w - z.w;
  float4 st;
  st.x = z.x + dx; st.y = z.y + dy; st.z = z.z + dz; st.w = z.w + dw;
  float* dst = (k < LDIM) ? (out + OFF_REAL + (size_t)row * LDIM + k)
                          : (out + OFF_IMAG + (size_t)row * LDIM + (k - LDIM));
  *reinterpret_cast<float4*>(dst) = st;
  const float4 sw = *reinterpret_cast<const float4*>(sal_w + k);
  const float4 cw = *reinterpret_cast<const float4*>(conf_w + k);
  const float sdot = st.x*sw.x + st.y*sw.y + st.z*sw.z + st.w*sw.w;
  const float cdot = st.x*cw.x + st.y*cw.y + st.z*cw.z + st.w*cw.w;
  const float dif = dx*dx + dy*dy + dz*dz + dw*dw;
  __shared__ float r1[256], r2[256], r3[256];
  r1[t] = sdot; r2[t] = cdot; r3[t] = dif;
  __syncthreads();
  for (int s = 128; s > 0; s >>= 1) {
    if (t < s) { r1[t] += r1[t + s]; r2[t] += r2[t + s]; r3[t] += r3[t + s]; }
    __syncthreads();
  }
  if (t == 0) {
    out[OFF_SAL + row]  = r1[0] + sal_b[0] + 0.1f * (-minfinal[row]);
    out[OFF_CONF + row] = 1.0f / (1.0f + expf(-(r2[0] + conf_b[0])));
    rowloss[row] = r3[0];
  }
}

__global__ __launch_bounds__(256)
void loss_kernel(const float* __restrict__ rowloss, float* __restrict__ out) {
  const int t = threadIdx.x;
  float s = 0.f;
  for (int i = t; i < RDIM; i += 256) s += rowloss[i];
  __shared__ float red[256];
  red[t] = s;
  __syncthreads();
  for (int st = 128; st > 0; st >>= 1) {
    if (t < st) red[t] += red[t + st];
    __syncthreads();
  }
  if (t == 0) {
    const float m = red[0] / (float)((size_t)RDIM * DDIM);
    out[OFF_LOSS] = m + 0.01f * m;
  }
}

// ============ FALLBACK (round-1 fp32 path) ============

__global__ __launch_bounds__(256)
void norms_kernel(const float* __restrict__ gw_real, const float* __restrict__ gw_imag,
                  const float* __restrict__ codebook,
                  float* __restrict__ znorm, float* __restrict__ cnorm) {
  const int id = blockIdx.x;
  const int t = threadIdx.x;
  float s;
  if (id < RDIM) {
    const float4* zr = reinterpret_cast<const float4*>(gw_real + (size_t)id * LDIM);
    const float4* zi = reinterpret_cast<const float4*>(gw_imag + (size_t)id * LDIM);
    const float4 v = (t < 128) ? zr[t] : zi[t - 128];
    s = v.x*v.x + v.y*v.y + v.z*v.z + v.w*v.w;
  } else {
    const float4* c = reinterpret_cast<const float4*>(codebook + (size_t)(id - RDIM) * DDIM);
    const float4 v = c[t];
    s = v.x*v.x + v.y*v.y + v.z*v.z + v.w*v.w;
  }
  __shared__ float red[256];
  red[t] = s;
  __syncthreads();
  for (int st = 128; st > 0; st >>= 1) {
    if (t < st) red[t] += red[t + st];
    __syncthreads();
  }
  if (t == 0) {
    if (id < RDIM) znorm[id] = red[0];
    else           cnorm[id - RDIM] = red[0];
  }
}

__global__ __launch_bounds__(256)
void dist_kernel(const float* __restrict__ gw_real, const float* __restrict__ gw_imag,
                 const float* __restrict__ codebook, const int* __restrict__ prev,
                 const float* __restrict__ adj, const float* __restrict__ znorm,
                 const float* __restrict__ cnorm,
                 float* __restrict__ ws_min, int* __restrict__ ws_idx) {
  __shared__ float As[16][64];
  __shared__ float Bs[16][64];
  __shared__ int prevs[64];
  const int bm = blockIdx.x, bn = blockIdx.y;
  const int row0 = bm * 64, col0 = bn * 64;
  const int tid = threadIdx.x;
  const int tx = tid & 15, ty = tid >> 4;
  if (tid < 64) prevs[tid] = prev[row0 + tid];
  const int lm = tid >> 2;
  const int lk = (tid & 3) << 2;
  const int arow = row0 + lm;
  const int brow = col0 + lm;
  float acc[4][4] = {{0.f,0.f,0.f,0.f},{0.f,0.f,0.f,0.f},{0.f,0.f,0.f,0.f},{0.f,0.f,0.f,0.f}};
  for (int kk = 0; kk < DDIM; kk += 16) {
    const int k = kk + lk;
    float4 a, b;
    if (k < LDIM) a = *reinterpret_cast<const float4*>(gw_real + (size_t)arow * LDIM + k);
    else          a = *reinterpret_cast<const float4*>(gw_imag + (size_t)arow * LDIM + (k - LDIM));
    b = *reinterpret_cast<const float4*>(codebook + (size_t)brow * DDIM + k);
    __syncthreads();
    As[lk+0][lm]=a.x; As[lk+1][lm]=a.y; As[lk+2][lm]=a.z; As[lk+3][lm]=a.w;
    Bs[lk+0][lm]=b.x; Bs[lk+1][lm]=b.y; Bs[lk+2][lm]=b.z; Bs[lk+3][lm]=b.w;
    __syncthreads();
#pragma unroll
    for (int k2 = 0; k2 < 16; ++k2) {
      const float4 a4 = *reinterpret_cast<const float4*>(&As[k2][ty << 2]);
      const float4 b4 = *reinterpret_cast<const float4*>(&Bs[k2][tx << 2]);
      const float av[4] = {a4.x, a4.y, a4.z, a4.w};
      const float bv[4] = {b4.x, b4.y, b4.z, b4.w};
#pragma unroll
      for (int i = 0; i < 4; ++i)
#pragma unroll
        for (int j = 0; j < 4; ++j)
          acc[i][j] = fmaf(av[i], bv[j], acc[i][j]);
    }
  }
  const float4 cn4 = *reinterpret_cast<const float4*>(cnorm + col0 + (tx << 2));
  const float cnv[4] = {cn4.x, cn4.y, cn4.z, cn4.w};
#pragma unroll
  for (int i = 0; i < 4; ++i) {
    const int rsub = (ty << 2) + i;
    const int row = row0 + rsub;
    const float zn = znorm[row];
    const int p = prevs[rsub];
    const float4 ad4 = *reinterpret_cast<const float4*>(adj + (size_t)p * NDIM + col0 + (tx << 2));
    const float adv[4] = {ad4.x, ad4.y, ad4.z, ad4.w};
    float bv = FLT_BIG;
    int bi = -1;
#pragma unroll
    for (int j = 0; j < 4; ++j) {
      const float bias = 0.8f * (1.0f / (1.0f + expf(-adv[j])));
      const float dv = (zn + cnv[j]) - 2.0f * acc[i][j] - bias;
      const int col = col0 + (tx << 2) + j;
      if (dv < bv) { bv = dv; bi = col; }
    }
    for (int m = 1; m < 16; m <<= 1) {
      const float ov = __shfl_xor(bv, m, 64);
      const int   oi = __shfl_xor(bi, m, 64);
      if (ov < bv || (ov == bv && oi < bi)) { bv = ov; bi = oi; }
    }
    if (tx == 0) {
      ws_min[(size_t)row * 128 + bn] = bv;
      ws_idx[(size_t)row * 128 + bn] = bi;
    }
  }
}

__global__ __launch_bounds__(128)
void argmin_reduce(const float* __restrict__ ws_min, const int* __restrict__ ws_idx,
                   float* __restrict__ out, float* __restrict__ minfinal,
                   int* __restrict__ idxfinal) {
  const int row = blockIdx.x;
  const int t = threadIdx.x;
  __shared__ float sv[128];
  __shared__ int   si[128];
  sv[t] = ws_min[(size_t)row * 128 + t];
  si[t] = ws_idx[(size_t)row * 128 + t];
  __syncthreads();
  for (int s = 64; s > 0; s >>= 1) {
    if (t < s) {
      const float ov = sv[t + s];
      const int   oi = si[t + s];
      if (ov < sv[t] || (ov == sv[t] && oi < si[t])) { sv[t] = ov; si[t] = oi; }
    }
    __syncthreads();
  }
  if (t == 0) {
    out[OFF_IDX + row] = (float)si[0];
    minfinal[row] = sv[0];
    idxfinal[row] = si[0];
  }
}

// ============ HOST ============

extern "C" void kernel_launch(void* const* d_in, const int* in_sizes, int n_in,
                              void* d_out, int out_size, void* d_ws, size_t ws_size,
                              hipStream_t stream) {
  const float* gw_real  = (const float*)d_in[0];
  const float* gw_imag  = (const float*)d_in[1];
  const int*   prev     = (const int*)d_in[2];
  const float* codebook = (const float*)d_in[3];
  const float* adj      = (const float*)d_in[4];
  const float* sal_w    = (const float*)d_in[5];
  const float* sal_b    = (const float*)d_in[6];
  const float* conf_w   = (const float*)d_in[7];
  const float* conf_b   = (const float*)d_in[8];
  float* out = (float*)d_out;
  char* ws = (char*)d_ws;

  const size_t matsz = (size_t)RDIM * DDIM;              // bf16 elements per matrix
  const size_t qsz   = (size_t)RDIM * NDIM;              // int16 score matrix
  size_t need = 2 * matsz * 2                            // zh, ch (bf16)
              + qsz * 2                                  // q (int16)
              + (size_t)RDIM * MAXCAND * 4               // gcand
              + 6 * (size_t)RDIM * 4 + 4096;             // gcount,znorm,cnorm,minfinal,idxfinal,rowloss

  if (ws_size >= need) {
    unsigned short* zh = (unsigned short*)ws;
    unsigned short* chh = zh + matsz;
    short* q = (short*)(chh + matsz);
    int*   gcand  = (int*)(q + qsz);
    int*   gcount = gcand + (size_t)RDIM * MAXCAND;
    float* znorm    = (float*)(gcount + RDIM);
    float* cnorm    = znorm + RDIM;
    float* minfinal = cnorm + NDIM;
    int*   idxfinal = (int*)(minfinal + RDIM);
    float* rowloss  = (float*)(idxfinal + RDIM);

    split_norms_kernel<<<RDIM + NDIM, 256, 0, stream>>>(gw_real, gw_imag, codebook,
                                                        zh, chh, znorm, cnorm);
    dist_mfma_kernel<<<256, 512, 0, stream>>>(zh, chh, cnorm, q);
    collect_kernel<<<RDIM, 256, 0, stream>>>(q, prev, adj, znorm,
                                             out, minfinal, idxfinal, gcount, gcand);
    refine_kernel<<<RDIM, 64, 0, stream>>>(gw_real, gw_imag, codebook, prev, adj,
                                           znorm, cnorm, gcount, gcand,
                                           out, minfinal, idxfinal);
    epilogue_kernel<<<RDIM, 256, 0, stream>>>(gw_real, gw_imag, codebook, sal_w, sal_b,
                                              conf_w, conf_b, minfinal, idxfinal, out, rowloss);
    loss_kernel<<<1, 256, 0, stream>>>(rowloss, out);
  } else {
    float* ws_min   = (float*)ws;
    int*   ws_idx   = (int*)(ws + (size_t)RDIM * 128 * 4);
    float* znorm    = (float*)(ws + (size_t)RDIM * 128 * 8);
    float* cnorm    = znorm + RDIM;
    float* minfinal = cnorm + NDIM;
    int*   idxfinal = (int*)(minfinal + RDIM);
    float* rowloss  = (float*)(idxfinal + RDIM);

    norms_kernel<<<RDIM + NDIM, 256, 0, stream>>>(gw_real, gw_imag, codebook, znorm, cnorm);
    dist_kernel<<<dim3(RDIM / 64, NDIM / 64), 256, 0, stream>>>(
        gw_real, gw_imag, codebook, prev, adj, znorm, cnorm, ws_min, ws_idx);
    argmin_reduce<<<RDIM, 128, 0, stream>>>(ws_min, ws_idx, out, minfinal, idxfinal);
    epilogue_kernel<<<RDIM, 256, 0, stream>>>(gw_real, gw_imag, codebook, sal_w, sal_b,
                                              conf_w, conf_b, minfinal, idxfinal, out, rowloss);
    loss_kernel<<<1, 256, 0, stream>>>(rowloss, out);
  }
}

// Round 10
// 223.509 us; speedup vs baseline: 1.6669x; 1.0179x over previous
//
#include <hip/hip_runtime.h>
#include <math.h>

#define RDIM 8192   // B*S
#define DDIM 1024   // 2*L
#define NDIM 8192
#define LDIM 512
#define KT 16       // K-steps of 64 over K=1024

#define OFF_REAL 0
#define OFF_IMAG 4194304
#define OFF_SAL  8388608
#define OFF_CONF 8396800
#define OFF_LOSS 8404992
#define OFF_IDX  8404993

#define MAXCAND 64
#define MARGIN_Q 76        // 1.1875 units of d: 0.8 bias range + bf16 pair err + quant
#define QSCALE 64.0f
#define FLT_BIG 3.4e38f

typedef __attribute__((ext_vector_type(8))) short bf16x8;
typedef __attribute__((ext_vector_type(8))) short short8v;
typedef __attribute__((ext_vector_type(4))) float f32x4;

__device__ __forceinline__ unsigned short f2bf(float x) {
  unsigned u = __builtin_bit_cast(unsigned, x);
  unsigned r = (u + 0x7fff + ((u >> 16) & 1)) >> 16;
  return (unsigned short)r;
}

__device__ __forceinline__ void load_lds16(const void* g, void* l) {
  __builtin_amdgcn_global_load_lds((const __attribute__((address_space(1))) void*)g,
                                   (__attribute__((address_space(3))) void*)l, 16, 0, 0);
}

__device__ __forceinline__ short clampq(float s) {
  int qi = __float2int_rn(s * QSCALE);
  qi = qi > 32767 ? 32767 : (qi < -32767 ? -32767 : qi);
  return (short)qi;
}

// ============ bf16 cast + exact fp32 norms (wave-per-row, shuffle-only) ============
__global__ __launch_bounds__(256)
void split_norms_kernel(const float* __restrict__ gw_real, const float* __restrict__ gw_imag,
                        const float* __restrict__ codebook,
                        unsigned short* __restrict__ zh, unsigned short* __restrict__ ch,
                        float* __restrict__ znorm, float* __restrict__ cnorm) {
  const int w = threadIdx.x >> 6, l = threadIdx.x & 63;
  const int id = blockIdx.x * 4 + w;     // [0, 16384)
  const float* src;
  unsigned short* dst;
  float* nrm;
  int row;
  if (id < RDIM) {
    row = id; dst = zh; nrm = znorm;
    src = (l < 32) ? gw_real + (size_t)row * LDIM + l * 16
                   : gw_imag + (size_t)row * LDIM + (l - 32) * 16;
  } else {
    row = id - RDIM; dst = ch; nrm = cnorm;
    src = codebook + (size_t)row * DDIM + l * 16;
  }
  float f[16];
#pragma unroll
  for (int i = 0; i < 4; ++i) {
    const float4 v = reinterpret_cast<const float4*>(src)[i];
    f[i*4+0] = v.x; f[i*4+1] = v.y; f[i*4+2] = v.z; f[i*4+3] = v.w;
  }
  short8v h0, h1;
  float s = 0.f;
#pragma unroll
  for (int i = 0; i < 8; ++i) { h0[i] = (short)f2bf(f[i]);     s += f[i] * f[i]; }
#pragma unroll
  for (int i = 0; i < 8; ++i) { h1[i] = (short)f2bf(f[8 + i]); s += f[8+i] * f[8+i]; }
  unsigned short* dp = dst + (size_t)row * DDIM + l * 16;
  *reinterpret_cast<short8v*>(dp)     = h0;
  *reinterpret_cast<short8v*>(dp + 8) = h1;
#pragma unroll
  for (int m = 1; m < 64; m <<= 1) s += __shfl_xor(s, m, 64);
  if (l == 0) nrm[row] = s;
}

// ============ 256x256 tile, BK=64, 8-wave 4-phase bf16 GEMM (r6-exact, measured best) ============
#define STAGE(basep, kt, ldsbyte) do {                                        \
    load_lds16((basep) + eo1 + (kt) * 64, L + (ldsbyte) + wid * 1024);        \
    load_lds16((basep) + eo2 + (kt) * 64, L + (ldsbyte) + 8192 + wid * 1024); \
  } while (0)

__global__ __launch_bounds__(512)
void dist_mfma_kernel(const unsigned short* __restrict__ zh, const unsigned short* __restrict__ ch,
                      const float* __restrict__ cnorm, short* __restrict__ q) {
  __shared__ unsigned short ldsbuf[65536];   // 128 KB: [buf][A 32K | B 32K]
  char* const L = (char*)ldsbuf;

  // XCD-aware swizzle (1024 blocks = 8 XCDs x 128, bijective)
  const int sidx = (int)blockIdx.x;
  const int sw = (sidx & 7) * 128 + (sidx >> 3);
  const int bm = sw >> 5, bn = sw & 31;
  const int row0 = bm * 256, col0 = bn * 256;

  const int tid = threadIdx.x;
  const int wid = tid >> 6, l = tid & 63;
  const int wm = wid >> 2, wn = wid & 3;       // 2 x 4 wave grid
  const int lr = l & 15, lg = l >> 4;

  // ---- staging geometry: half-tile = 128 rows x 64 cols bf16 = 1024 chunks of 16B
  const int p1 = tid, p2 = tid + 512;
  const int r1 = p1 >> 3, c1 = (p1 & 7) ^ (r1 & 7);
  const int r2 = p2 >> 3, c2 = (p2 & 7) ^ (r2 & 7);
  const int eo1 = r1 * DDIM + c1 * 8;
  const int eo2 = r2 * DDIM + c2 * 8;
  const unsigned short* const az0 = zh + (size_t)row0 * DDIM;
  const unsigned short* const az1 = zh + (size_t)(row0 + 128) * DDIM;
  const unsigned short* const ac0 = ch + (size_t)col0 * DDIM;
  const unsigned short* const ac1 = ch + (size_t)(col0 + 128) * DDIM;

  // ---- fragment read offsets (row = base + lr, chunk' = (kh*4+lg) ^ (lr&7))
  const int fo0 = lr * 128 + ((lg ^ (lr & 7)) << 4);
  const int fo1 = fo0 ^ 64;

  f32x4 acc[4][8];
#pragma unroll
  for (int i = 0; i < 4; ++i)
#pragma unroll
    for (int j = 0; j < 8; ++j)
      acc[i][j] = (f32x4){0.f, 0.f, 0.f, 0.f};

  bf16x8 cfA[2][2], cfB[2][2], zf[4][2];

  // ---- prologue: tile0 (A+B) into buf0, B(1) into buf1; A(1) staged inside loop t=0
  STAGE(az0, 0, 0);
  STAGE(az1, 0, 16384);
  STAGE(ac0, 0, 32768);
  STAGE(ac1, 0, 49152);
  STAGE(ac0, 1, 98304);
  STAGE(ac1, 1, 114688);
  asm volatile("s_waitcnt vmcnt(4)" ::: "memory");   // tile0 landed; B(1) may fly
  __builtin_amdgcn_sched_barrier(0);
  __builtin_amdgcn_s_barrier();

  for (int t = 0; t < KT; ++t) {
    const int buf = t & 1, nbuf = buf ^ 1;
    const char* const Ab = L + buf * 65536 + wm * 16384;          // wave's z-half
    const char* const Bb = L + buf * 65536 + 32768 + wn * 8192;   // wave's c-64-block

    // ======== P1: quadrant (mf 0-1, nf 0-3); stage A0(t+1) ========
#pragma unroll
    for (int i = 0; i < 2; ++i) {
      cfA[i][0] = *reinterpret_cast<const bf16x8*>(Bb + i * 2048 + fo0);
      cfA[i][1] = *reinterpret_cast<const bf16x8*>(Bb + i * 2048 + fo1);
    }
#pragma unroll
    for (int j = 0; j < 4; ++j) {
      zf[j][0] = *reinterpret_cast<const bf16x8*>(Ab + j * 2048 + fo0);
      zf[j][1] = *reinterpret_cast<const bf16x8*>(Ab + j * 2048 + fo1);
    }
    if (t + 1 < KT) STAGE(az0, t + 1, nbuf * 65536);
    __builtin_amdgcn_sched_barrier(0);
    __builtin_amdgcn_s_barrier();
    __builtin_amdgcn_s_setprio(1);
#pragma unroll
    for (int kh = 0; kh < 2; ++kh)
#pragma unroll
      for (int i = 0; i < 2; ++i)
#pragma unroll
        for (int j = 0; j < 4; ++j)
          acc[i][j] = __builtin_amdgcn_mfma_f32_16x16x32_bf16(cfA[i][kh], zf[j][kh], acc[i][j], 0, 0, 0);
    __builtin_amdgcn_s_setprio(0);
    __builtin_amdgcn_sched_barrier(0);
    __builtin_amdgcn_s_barrier();

    // ======== P2: quadrant (mf 2-3, nf 0-3); stage A1(t+1) ========
#pragma unroll
    for (int i = 0; i < 2; ++i) {
      cfB[i][0] = *reinterpret_cast<const bf16x8*>(Bb + (2 + i) * 2048 + fo0);
      cfB[i][1] = *reinterpret_cast<const bf16x8*>(Bb + (2 + i) * 2048 + fo1);
    }
    if (t + 1 < KT) STAGE(az1, t + 1, nbuf * 65536 + 16384);
    __builtin_amdgcn_sched_barrier(0);
    __builtin_amdgcn_s_barrier();
    __builtin_amdgcn_s_setprio(1);
#pragma unroll
    for (int kh = 0; kh < 2; ++kh)
#pragma unroll
      for (int i = 0; i < 2; ++i)
#pragma unroll
        for (int j = 0; j < 4; ++j)
          acc[2 + i][j] = __builtin_amdgcn_mfma_f32_16x16x32_bf16(cfB[i][kh], zf[j][kh], acc[2 + i][j], 0, 0, 0);
    __builtin_amdgcn_s_setprio(0);
    __builtin_amdgcn_sched_barrier(0);
    __builtin_amdgcn_s_barrier();

    // ======== P3: quadrant (mf 2-3, nf 4-7); stage B0(t+2) into current buf ========
#pragma unroll
    for (int j = 0; j < 4; ++j) {
      zf[j][0] = *reinterpret_cast<const bf16x8*>(Ab + (4 + j) * 2048 + fo0);
      zf[j][1] = *reinterpret_cast<const bf16x8*>(Ab + (4 + j) * 2048 + fo1);
    }
    if (t + 2 < KT) STAGE(ac0, t + 2, buf * 65536 + 32768);
    __builtin_amdgcn_sched_barrier(0);
    __builtin_amdgcn_s_barrier();
    __builtin_amdgcn_s_setprio(1);
#pragma unroll
    for (int kh = 0; kh < 2; ++kh)
#pragma unroll
      for (int i = 0; i < 2; ++i)
#pragma unroll
        for (int j = 0; j < 4; ++j)
          acc[2 + i][4 + j] = __builtin_amdgcn_mfma_f32_16x16x32_bf16(cfB[i][kh], zf[j][kh], acc[2 + i][4 + j], 0, 0, 0);
    __builtin_amdgcn_s_setprio(0);
    __builtin_amdgcn_sched_barrier(0);
    __builtin_amdgcn_s_barrier();

    // ======== P4: quadrant (mf 0-1, nf 4-7); stage B1(t+2); counted vmcnt ========
    if (t + 2 < KT) STAGE(ac1, t + 2, buf * 65536 + 49152);
    if (t < KT - 2) { asm volatile("s_waitcnt vmcnt(4)" ::: "memory"); }
    else            { asm volatile("s_waitcnt vmcnt(0)" ::: "memory"); }
    __builtin_amdgcn_sched_barrier(0);
    __builtin_amdgcn_s_barrier();
    __builtin_amdgcn_s_setprio(1);
#pragma unroll
    for (int kh = 0; kh < 2; ++kh)
#pragma unroll
      for (int i = 0; i < 2; ++i)
#pragma unroll
        for (int j = 0; j < 4; ++j)
          acc[i][4 + j] = __builtin_amdgcn_mfma_f32_16x16x32_bf16(cfA[i][kh], zf[j][kh], acc[i][4 + j], 0, 0, 0);
    __builtin_amdgcn_s_setprio(0);
    __builtin_amdgcn_sched_barrier(0);
    __builtin_amdgcn_s_barrier();
  }

  // ---- epilogue: s = cn - 2*dot, quantize, cached short4 stores
  const int czero = col0 + wn * 64;
  const int zzero = row0 + wm * 128;
#pragma unroll
  for (int i = 0; i < 4; ++i) {
    const int cc = czero + i * 16 + lg * 4;
    const float4 cn4 = *reinterpret_cast<const float4*>(cnorm + cc);
#pragma unroll
    for (int j = 0; j < 8; ++j) {
      const int zr = zzero + j * 16 + lr;
      const f32x4 a = acc[i][j];
      *reinterpret_cast<short4*>(q + (size_t)zr * NDIM + cc) =
          make_short4(clampq(cn4.x - 2.0f * a[0]), clampq(cn4.y - 2.0f * a[1]),
                      clampq(cn4.z - 2.0f * a[2]), clampq(cn4.w - 2.0f * a[3]));
    }
  }
}

// ============ streaming per-row min + candidate collection + inline exact refine ============
__global__ __launch_bounds__(256)
void collect_refine_kernel(const short* __restrict__ q, const int* __restrict__ prev,
                           const float* __restrict__ adj,
                           const float* __restrict__ gw_real, const float* __restrict__ gw_imag,
                           const float* __restrict__ codebook,
                           const float* __restrict__ znorm, const float* __restrict__ cnorm,
                           float* __restrict__ out, float* __restrict__ minfinal,
                           int* __restrict__ idxfinal) {
  __shared__ unsigned s_wmin[4];
  __shared__ int s_cnt;
  __shared__ int s_list[MAXCAND];
  __shared__ float s_bv[4];
  __shared__ int   s_bi[4];
  const int row = blockIdx.x;
  const int t = threadIdx.x;    // 256
  if (t == 0) s_cnt = 0;
  short8v v[4];
  unsigned kmin = 0xffffffffu;
#pragma unroll
  for (int c = 0; c < 4; ++c) {
    v[c] = *reinterpret_cast<const short8v*>(q + (size_t)row * NDIM + (c * 256 + t) * 8);
#pragma unroll
    for (int j = 0; j < 8; ++j) {
      const int col = (c * 256 + t) * 8 + j;
      const unsigned key = (((unsigned)((int)v[c][j] + 32768)) << 13) | (unsigned)col;
      kmin = (key < kmin) ? key : kmin;     // lex (q, col) min
    }
  }
  for (int m = 1; m < 64; m <<= 1) {
    const unsigned o = (unsigned)__shfl_xor((int)kmin, m, 64);
    kmin = (o < kmin) ? o : kmin;
  }
  if ((t & 63) == 0) s_wmin[t >> 6] = kmin;
  __syncthreads();
  unsigned gk = s_wmin[0];
  gk = gk < s_wmin[1] ? gk : s_wmin[1];
  gk = gk < s_wmin[2] ? gk : s_wmin[2];
  gk = gk < s_wmin[3] ? gk : s_wmin[3];
  const int qmin = (int)(gk >> 13) - 32768;
  const int winner = (int)(gk & 8191u);
  const int thr = qmin + MARGIN_Q;
#pragma unroll
  for (int c = 0; c < 4; ++c) {
#pragma unroll
    for (int j = 0; j < 8; ++j) {
      if ((int)v[c][j] <= thr) {
        const int pos = atomicAdd(&s_cnt, 1);
        if (pos < MAXCAND) s_list[pos] = (c * 256 + t) * 8 + j;
      }
    }
  }
  __syncthreads();
  const int cnt = (s_cnt < MAXCAND) ? s_cnt : MAXCAND;
  if (cnt <= 1) {
    if (t == 0) {
      const int p = prev[row];
      const float bias = 0.8f / (1.0f + expf(-adj[(size_t)p * NDIM + winner]));
      out[OFF_IDX + row] = (float)winner;
      idxfinal[row] = winner;
      minfinal[row] = znorm[row] + (float)qmin * (1.0f / QSCALE) - bias;
    }
    return;
  }
  // ---- inline exact fp32 refine: 4 waves process 4 candidates in parallel ----
  const int w = t >> 6, l = t & 63;
  const int base = l * 16;
  const float* zp = (base < LDIM) ? gw_real + (size_t)row * LDIM + base
                                  : gw_imag + (size_t)row * LDIM + (base - LDIM);
  float z[16];
#pragma unroll
  for (int c = 0; c < 4; ++c) {
    const float4 zv = reinterpret_cast<const float4*>(zp)[c];
    z[c*4+0] = zv.x; z[c*4+1] = zv.y; z[c*4+2] = zv.z; z[c*4+3] = zv.w;
  }
  const float zn = znorm[row];
  const int p = prev[row];
  float bestd = FLT_BIG;
  int besti = 0x7fffffff;
  for (int j = w; j < cnt; j += 4) {
    const int idx = s_list[j];
    const float* cp = codebook + (size_t)idx * DDIM + base;
    float dot = 0.f;
#pragma unroll
    for (int c = 0; c < 4; ++c) {
      const float4 cv = reinterpret_cast<const float4*>(cp)[c];
      dot += z[c*4+0]*cv.x + z[c*4+1]*cv.y + z[c*4+2]*cv.z + z[c*4+3]*cv.w;
    }
    for (int m = 1; m < 64; m <<= 1) dot += __shfl_xor(dot, m, 64);
    const float d = zn + cnorm[idx] - 2.0f * dot
                  - 0.8f / (1.0f + expf(-adj[(size_t)p * NDIM + idx]));
    if (d < bestd || (d == bestd && idx < besti)) { bestd = d; besti = idx; }
  }
  if (l == 0) { s_bv[w] = bestd; s_bi[w] = besti; }
  __syncthreads();
  if (t == 0) {
    float bv = s_bv[0]; int bi = s_bi[0];
#pragma unroll
    for (int w2 = 1; w2 < 4; ++w2) {
      const float ov = s_bv[w2]; const int oi = s_bi[w2];
      if (ov < bv || (ov == bv && oi < bi)) { bv = ov; bi = oi; }
    }
    out[OFF_IDX + row] = (float)bi;
    minfinal[row] = bv;
    idxfinal[row] = bi;
  }
}

// ============ SHARED EPILOGUE (wave-reduce) ============

__global__ __launch_bounds__(256)
void epilogue_kernel(const float* __restrict__ gw_real, const float* __restrict__ gw_imag,
                     const float* __restrict__ codebook,
                     const float* __restrict__ sal_w, const float* __restrict__ sal_b,
                     const float* __restrict__ conf_w, const float* __restrict__ conf_b,
                     const float* __restrict__ minfinal, const int* __restrict__ idxfinal,
                     float* __restrict__ out, float* __restrict__ rowloss) {
  __shared__ float s1[4], s2[4], s3[4];
  const int row = blockIdx.x;
  const int t = threadIdx.x;
  const int w = t >> 6, l = t & 63;
  const int k = t << 2;
  const int idx = idxfinal[row];
  const float4 qv = *reinterpret_cast<const float4*>(codebook + (size_t)idx * DDIM + k);
  float4 z;
  if (k < LDIM) z = *reinterpret_cast<const float4*>(gw_real + (size_t)row * LDIM + k);
  else          z = *reinterpret_cast<const float4*>(gw_imag + (size_t)row * LDIM + (k - LDIM));
  const float dx = qv.x - z.x, dy = qv.y - z.y, dz = qv.z - z.z, dw = qv.w - z.w;
  float4 st;
  st.x = z.x + dx; st.y = z.y + dy; st.z = z.z + dz; st.w = z.w + dw;
  float* dst = (k < LDIM) ? (out + OFF_REAL + (size_t)row * LDIM + k)
                          : (out + OFF_IMAG + (size_t)row * LDIM + (k - LDIM));
  *reinterpret_cast<float4*>(dst) = st;
  const float4 sw = *reinterpret_cast<const float4*>(sal_w + k);
  const float4 cw = *reinterpret_cast<const float4*>(conf_w + k);
  float r1 = st.x*sw.x + st.y*sw.y + st.z*sw.z + st.w*sw.w;
  float r2 = st.x*cw.x + st.y*cw.y + st.z*cw.z + st.w*cw.w;
  float r3 = dx*dx + dy*dy + dz*dz + dw*dw;
#pragma unroll
  for (int m = 1; m < 64; m <<= 1) {
    r1 += __shfl_xor(r1, m, 64);
    r2 += __shfl_xor(r2, m, 64);
    r3 += __shfl_xor(r3, m, 64);
  }
  if (l == 0) { s1[w] = r1; s2[w] = r2; s3[w] = r3; }
  __syncthreads();
  if (t == 0) {
    const float t1 = s1[0] + s1[1] + s1[2] + s1[3];
    const float t2 = s2[0] + s2[1] + s2[2] + s2[3];
    const float t3 = s3[0] + s3[1] + s3[2] + s3[3];
    out[OFF_SAL + row]  = t1 + sal_b[0] + 0.1f * (-minfinal[row]);
    out[OFF_CONF + row] = 1.0f / (1.0f + expf(-(t2 + conf_b[0])));
    rowloss[row] = t3;
  }
}

__global__ __launch_bounds__(256)
void loss_kernel(const float* __restrict__ rowloss, float* __restrict__ out) {
  const int t = threadIdx.x;
  float s = 0.f;
  for (int i = t; i < RDIM; i += 256) s += rowloss[i];
  __shared__ float red[256];
  red[t] = s;
  __syncthreads();
  for (int st = 128; st > 0; st >>= 1) {
    if (t < st) red[t] += red[t + st];
    __syncthreads();
  }
  if (t == 0) {
    const float m = red[0] / (float)((size_t)RDIM * DDIM);
    out[OFF_LOSS] = m + 0.01f * m;
  }
}

// ============ FALLBACK (round-1 fp32 path) ============

__global__ __launch_bounds__(256)
void norms_kernel(const float* __restrict__ gw_real, const float* __restrict__ gw_imag,
                  const float* __restrict__ codebook,
                  float* __restrict__ znorm, float* __restrict__ cnorm) {
  const int id = blockIdx.x;
  const int t = threadIdx.x;
  float s;
  if (id < RDIM) {
    const float4* zr = reinterpret_cast<const float4*>(gw_real + (size_t)id * LDIM);
    const float4* zi = reinterpret_cast<const float4*>(gw_imag + (size_t)id * LDIM);
    const float4 v = (t < 128) ? zr[t] : zi[t - 128];
    s = v.x*v.x + v.y*v.y + v.z*v.z + v.w*v.w;
  } else {
    const float4* c = reinterpret_cast<const float4*>(codebook + (size_t)(id - RDIM) * DDIM);
    const float4 v = c[t];
    s = v.x*v.x + v.y*v.y + v.z*v.z + v.w*v.w;
  }
  __shared__ float red[256];
  red[t] = s;
  __syncthreads();
  for (int st = 128; st > 0; st >>= 1) {
    if (t < st) red[t] += red[t + st];
    __syncthreads();
  }
  if (t == 0) {
    if (id < RDIM) znorm[id] = red[0];
    else           cnorm[id - RDIM] = red[0];
  }
}

__global__ __launch_bounds__(256)
void dist_kernel(const float* __restrict__ gw_real, const float* __restrict__ gw_imag,
                 const float* __restrict__ codebook, const int* __restrict__ prev,
                 const float* __restrict__ adj, const float* __restrict__ znorm,
                 const float* __restrict__ cnorm,
                 float* __restrict__ ws_min, int* __restrict__ ws_idx) {
  __shared__ float As[16][64];
  __shared__ float Bs[16][64];
  __shared__ int prevs[64];
  const int bm = blockIdx.x, bn = blockIdx.y;
  const int row0 = bm * 64, col0 = bn * 64;
  const int tid = threadIdx.x;
  const int tx = tid & 15, ty = tid >> 4;
  if (tid < 64) prevs[tid] = prev[row0 + tid];
  const int lm = tid >> 2;
  const int lk = (tid & 3) << 2;
  const int arow = row0 + lm;
  const int brow = col0 + lm;
  float acc[4][4] = {{0.f,0.f,0.f,0.f},{0.f,0.f,0.f,0.f},{0.f,0.f,0.f,0.f},{0.f,0.f,0.f,0.f}};
  for (int kk = 0; kk < DDIM; kk += 16) {
    const int k = kk + lk;
    float4 a, b;
    if (k < LDIM) a = *reinterpret_cast<const float4*>(gw_real + (size_t)arow * LDIM + k);
    else          a = *reinterpret_cast<const float4*>(gw_imag + (size_t)arow * LDIM + (k - LDIM));
    b = *reinterpret_cast<const float4*>(codebook + (size_t)brow * DDIM + k);
    __syncthreads();
    As[lk+0][lm]=a.x; As[lk+1][lm]=a.y; As[lk+2][lm]=a.z; As[lk+3][lm]=a.w;
    Bs[lk+0][lm]=b.x; Bs[lk+1][lm]=b.y; Bs[lk+2][lm]=b.z; Bs[lk+3][lm]=b.w;
    __syncthreads();
#pragma unroll
    for (int k2 = 0; k2 < 16; ++k2) {
      const float4 a4 = *reinterpret_cast<const float4*>(&As[k2][ty << 2]);
      const float4 b4 = *reinterpret_cast<const float4*>(&Bs[k2][tx << 2]);
      const float av[4] = {a4.x, a4.y, a4.z, a4.w};
      const float bv[4] = {b4.x, b4.y, b4.z, b4.w};
#pragma unroll
      for (int i = 0; i < 4; ++i)
#pragma unroll
        for (int j = 0; j < 4; ++j)
          acc[i][j] = fmaf(av[i], bv[j], acc[i][j]);
    }
  }
  const float4 cn4 = *reinterpret_cast<const float4*>(cnorm + col0 + (tx << 2));
  const float cnv[4] = {cn4.x, cn4.y, cn4.z, cn4.w};
#pragma unroll
  for (int i = 0; i < 4; ++i) {
    const int rsub = (ty << 2) + i;
    const int row = row0 + rsub;
    const float zn = znorm[row];
    const int p = prevs[rsub];
    const float4 ad4 = *reinterpret_cast<const float4*>(adj + (size_t)p * NDIM + col0 + (tx << 2));
    const float adv[4] = {ad4.x, ad4.y, ad4.z, ad4.w};
    float bv = FLT_BIG;
    int bi = -1;
#pragma unroll
    for (int j = 0; j < 4; ++j) {
      const float bias = 0.8f * (1.0f / (1.0f + expf(-adv[j])));
      const float dv = (zn + cnv[j]) - 2.0f * acc[i][j] - bias;
      const int col = col0 + (tx << 2) + j;
      if (dv < bv) { bv = dv; bi = col; }
    }
    for (int m = 1; m < 16; m <<= 1) {
      const float ov = __shfl_xor(bv, m, 64);
      const int   oi = __shfl_xor(bi, m, 64);
      if (ov < bv || (ov == bv && oi < bi)) { bv = ov; bi = oi; }
    }
    if (tx == 0) {
      ws_min[(size_t)row * 128 + bn] = bv;
      ws_idx[(size_t)row * 128 + bn] = bi;
    }
  }
}

__global__ __launch_bounds__(128)
void argmin_reduce(const float* __restrict__ ws_min, const int* __restrict__ ws_idx,
                   float* __restrict__ out, float* __restrict__ minfinal,
                   int* __restrict__ idxfinal) {
  const int row = blockIdx.x;
  const int t = threadIdx.x;
  __shared__ float sv[128];
  __shared__ int   si[128];
  sv[t] = ws_min[(size_t)row * 128 + t];
  si[t] = ws_idx[(size_t)row * 128 + t];
  __syncthreads();
  for (int s = 64; s > 0; s >>= 1) {
    if (t < s) {
      const float ov = sv[t + s];
      const int   oi = si[t + s];
      if (ov < sv[t] || (ov == sv[t] && oi < si[t])) { sv[t] = ov; si[t] = oi; }
    }
    __syncthreads();
  }
  if (t == 0) {
    out[OFF_IDX + row] = (float)si[0];
    minfinal[row] = sv[0];
    idxfinal[row] = si[0];
  }
}

// ============ HOST ============

extern "C" void kernel_launch(void* const* d_in, const int* in_sizes, int n_in,
                              void* d_out, int out_size, void* d_ws, size_t ws_size,
                              hipStream_t stream) {
  const float* gw_real  = (const float*)d_in[0];
  const float* gw_imag  = (const float*)d_in[1];
  const int*   prev     = (const int*)d_in[2];
  const float* codebook = (const float*)d_in[3];
  const float* adj      = (const float*)d_in[4];
  const float* sal_w    = (const float*)d_in[5];
  const float* sal_b    = (const float*)d_in[6];
  const float* conf_w   = (const float*)d_in[7];
  const float* conf_b   = (const float*)d_in[8];
  float* out = (float*)d_out;
  char* ws = (char*)d_ws;

  const size_t matsz = (size_t)RDIM * DDIM;              // bf16 elements per matrix
  const size_t qsz   = (size_t)RDIM * NDIM;              // int16 score matrix
  size_t need = 2 * matsz * 2                            // zh, ch (bf16)
              + qsz * 2                                  // q (int16)
              + 5 * (size_t)RDIM * 4 + 4096;             // znorm,cnorm,minfinal,idxfinal,rowloss

  if (ws_size >= need) {
    unsigned short* zh = (unsigned short*)ws;
    unsigned short* chh = zh + matsz;
    short* q = (short*)(chh + matsz);
    float* znorm    = (float*)(q + qsz);
    float* cnorm    = znorm + RDIM;
    float* minfinal = cnorm + NDIM;
    int*   idxfinal = (int*)(minfinal + RDIM);
    float* rowloss  = (float*)(idxfinal + RDIM);

    split_norms_kernel<<<(RDIM + NDIM) / 4, 256, 0, stream>>>(gw_real, gw_imag, codebook,
                                                              zh, chh, znorm, cnorm);
    dist_mfma_kernel<<<1024, 512, 0, stream>>>(zh, chh, cnorm, q);
    collect_refine_kernel<<<RDIM, 256, 0, stream>>>(q, prev, adj, gw_real, gw_imag, codebook,
                                                    znorm, cnorm, out, minfinal, idxfinal);
    epilogue_kernel<<<RDIM, 256, 0, stream>>>(gw_real, gw_imag, codebook, sal_w, sal_b,
                                              conf_w, conf_b, minfinal, idxfinal, out, rowloss);
    loss_kernel<<<1, 256, 0, stream>>>(rowloss, out);
  } else {
    float* ws_min   = (float*)ws;
    int*   ws_idx   = (int*)(ws + (size_t)RDIM * 128 * 4);
    float* znorm    = (float*)(ws + (size_t)RDIM * 128 * 8);
    float* cnorm    = znorm + RDIM;
    float* minfinal = cnorm + NDIM;
    int*   idxfinal = (int*)(minfinal + RDIM);
    float* rowloss  = (float*)(idxfinal + RDIM);

    norms_kernel<<<RDIM + NDIM, 256, 0, stream>>>(gw_real, gw_imag, codebook, znorm, cnorm);
    dist_kernel<<<dim3(RDIM / 64, NDIM / 64), 256, 0, stream>>>(
        gw_real, gw_imag, codebook, prev, adj, znorm, cnorm, ws_min, ws_idx);
    argmin_reduce<<<RDIM, 128, 0, stream>>>(ws_min, ws_idx, out, minfinal, idxfinal);
    epilogue_kernel<<<RDIM, 256, 0, stream>>>(gw_real, gw_imag, codebook, sal_w, sal_b,
                                              conf_w, conf_b, minfinal, idxfinal, out, rowloss);
    loss_kernel<<<1, 256, 0, stream>>>(rowloss, out);
  }
}

// Round 11
// 195.279 us; speedup vs baseline: 1.9078x; 1.1446x over previous
//
#include <hip/hip_runtime.h>
#include <math.h>

#define RDIM 8192   // B*S
#define DDIM 1024   // 2*L
#define NDIM 8192
#define LDIM 512
#define KT 16       // K-steps of 64 over K=1024

#define OFF_REAL 0
#define OFF_IMAG 4194304
#define OFF_SAL  8388608
#define OFF_CONF 8396800
#define OFF_LOSS 8404992
#define OFF_IDX  8404993

#define MAXCAND 64
#define MARGIN_Q 76        // 1.1875 units of d: 0.8 bias range + bf16 pair err + quant
#define QSCALE 64.0f
#define FLT_BIG 3.4e38f

typedef __attribute__((ext_vector_type(8))) short bf16x8;
typedef __attribute__((ext_vector_type(8))) short short8v;
typedef __attribute__((ext_vector_type(4))) float f32x4;

__device__ __forceinline__ unsigned short f2bf(float x) {
  unsigned u = __builtin_bit_cast(unsigned, x);
  unsigned r = (u + 0x7fff + ((u >> 16) & 1)) >> 16;
  return (unsigned short)r;
}

__device__ __forceinline__ void load_lds16(const void* g, void* l) {
  __builtin_amdgcn_global_load_lds((const __attribute__((address_space(1))) void*)g,
                                   (__attribute__((address_space(3))) void*)l, 16, 0, 0);
}

// quantize to biased int in [1, 65535]
__device__ __forceinline__ int qbias(float s) {
  int qi = __float2int_rn(s * QSCALE);
  qi = qi > 32767 ? 32767 : (qi < -32767 ? -32767 : qi);
  return qi + 32768;
}

// ============ bf16 cast + exact fp32 norms (wave-per-row, shuffle-only) ============
__global__ __launch_bounds__(256)
void split_norms_kernel(const float* __restrict__ gw_real, const float* __restrict__ gw_imag,
                        const float* __restrict__ codebook,
                        unsigned short* __restrict__ zh, unsigned short* __restrict__ ch,
                        float* __restrict__ znorm, float* __restrict__ cnorm) {
  const int w = threadIdx.x >> 6, l = threadIdx.x & 63;
  const int id = blockIdx.x * 4 + w;     // [0, 16384)
  const float* src;
  unsigned short* dst;
  float* nrm;
  int row;
  if (id < RDIM) {
    row = id; dst = zh; nrm = znorm;
    src = (l < 32) ? gw_real + (size_t)row * LDIM + l * 16
                   : gw_imag + (size_t)row * LDIM + (l - 32) * 16;
  } else {
    row = id - RDIM; dst = ch; nrm = cnorm;
    src = codebook + (size_t)row * DDIM + l * 16;
  }
  float f[16];
#pragma unroll
  for (int i = 0; i < 4; ++i) {
    const float4 v = reinterpret_cast<const float4*>(src)[i];
    f[i*4+0] = v.x; f[i*4+1] = v.y; f[i*4+2] = v.z; f[i*4+3] = v.w;
  }
  short8v h0, h1;
  float s = 0.f;
#pragma unroll
  for (int i = 0; i < 8; ++i) { h0[i] = (short)f2bf(f[i]);     s += f[i] * f[i]; }
#pragma unroll
  for (int i = 0; i < 8; ++i) { h1[i] = (short)f2bf(f[8 + i]); s += f[8+i] * f[8+i]; }
  unsigned short* dp = dst + (size_t)row * DDIM + l * 16;
  *reinterpret_cast<short8v*>(dp)     = h0;
  *reinterpret_cast<short8v*>(dp + 8) = h1;
#pragma unroll
  for (int m = 1; m < 64; m <<= 1) s += __shfl_xor(s, m, 64);
  if (l == 0) nrm[row] = s;
}

// ============ 256x256 tile, BK=64, 8-wave 4-phase bf16 GEMM (r6 loop verbatim) ============
// Epilogue: per (row, 64-col slice) lex-min key + 64-bit candidate bitmap (no q matrix).
#define STAGE(basep, kt, ldsbyte) do {                                        \
    load_lds16((basep) + eo1 + (kt) * 64, L + (ldsbyte) + wid * 1024);        \
    load_lds16((basep) + eo2 + (kt) * 64, L + (ldsbyte) + 8192 + wid * 1024); \
  } while (0)

__global__ __launch_bounds__(512)
void dist_mfma_kernel(const unsigned short* __restrict__ zh, const unsigned short* __restrict__ ch,
                      const float* __restrict__ cnorm,
                      unsigned* __restrict__ keys, unsigned long long* __restrict__ masks) {
  __shared__ unsigned short ldsbuf[65536];   // 128 KB: [buf][A 32K | B 32K]
  char* const L = (char*)ldsbuf;

  // XCD-aware swizzle (1024 blocks = 8 XCDs x 128, bijective)
  const int sidx = (int)blockIdx.x;
  const int sw = (sidx & 7) * 128 + (sidx >> 3);
  const int bm = sw >> 5, bn = sw & 31;
  const int row0 = bm * 256, col0 = bn * 256;

  const int tid = threadIdx.x;
  const int wid = tid >> 6, l = tid & 63;
  const int wm = wid >> 2, wn = wid & 3;       // 2 x 4 wave grid
  const int lr = l & 15, lg = l >> 4;

  // ---- staging geometry: half-tile = 128 rows x 64 cols bf16 = 1024 chunks of 16B
  const int p1 = tid, p2 = tid + 512;
  const int r1 = p1 >> 3, c1 = (p1 & 7) ^ (r1 & 7);
  const int r2 = p2 >> 3, c2 = (p2 & 7) ^ (r2 & 7);
  const int eo1 = r1 * DDIM + c1 * 8;
  const int eo2 = r2 * DDIM + c2 * 8;
  const unsigned short* const az0 = zh + (size_t)row0 * DDIM;
  const unsigned short* const az1 = zh + (size_t)(row0 + 128) * DDIM;
  const unsigned short* const ac0 = ch + (size_t)col0 * DDIM;
  const unsigned short* const ac1 = ch + (size_t)(col0 + 128) * DDIM;

  // ---- fragment read offsets (row = base + lr, chunk' = (kh*4+lg) ^ (lr&7))
  const int fo0 = lr * 128 + ((lg ^ (lr & 7)) << 4);
  const int fo1 = fo0 ^ 64;

  f32x4 acc[4][8];
#pragma unroll
  for (int i = 0; i < 4; ++i)
#pragma unroll
    for (int j = 0; j < 8; ++j)
      acc[i][j] = (f32x4){0.f, 0.f, 0.f, 0.f};

  bf16x8 cfA[2][2], cfB[2][2], zf[4][2];

  // ---- prologue: tile0 (A+B) into buf0, B(1) into buf1; A(1) staged inside loop t=0
  STAGE(az0, 0, 0);
  STAGE(az1, 0, 16384);
  STAGE(ac0, 0, 32768);
  STAGE(ac1, 0, 49152);
  STAGE(ac0, 1, 98304);
  STAGE(ac1, 1, 114688);
  asm volatile("s_waitcnt vmcnt(4)" ::: "memory");   // tile0 landed; B(1) may fly
  __builtin_amdgcn_sched_barrier(0);
  __builtin_amdgcn_s_barrier();

  for (int t = 0; t < KT; ++t) {
    const int buf = t & 1, nbuf = buf ^ 1;
    const char* const Ab = L + buf * 65536 + wm * 16384;          // wave's z-half
    const char* const Bb = L + buf * 65536 + 32768 + wn * 8192;   // wave's c-64-block

    // ======== P1: quadrant (mf 0-1, nf 0-3); stage A0(t+1) ========
#pragma unroll
    for (int i = 0; i < 2; ++i) {
      cfA[i][0] = *reinterpret_cast<const bf16x8*>(Bb + i * 2048 + fo0);
      cfA[i][1] = *reinterpret_cast<const bf16x8*>(Bb + i * 2048 + fo1);
    }
#pragma unroll
    for (int j = 0; j < 4; ++j) {
      zf[j][0] = *reinterpret_cast<const bf16x8*>(Ab + j * 2048 + fo0);
      zf[j][1] = *reinterpret_cast<const bf16x8*>(Ab + j * 2048 + fo1);
    }
    if (t + 1 < KT) STAGE(az0, t + 1, nbuf * 65536);
    __builtin_amdgcn_sched_barrier(0);
    __builtin_amdgcn_s_barrier();
    __builtin_amdgcn_s_setprio(1);
#pragma unroll
    for (int kh = 0; kh < 2; ++kh)
#pragma unroll
      for (int i = 0; i < 2; ++i)
#pragma unroll
        for (int j = 0; j < 4; ++j)
          acc[i][j] = __builtin_amdgcn_mfma_f32_16x16x32_bf16(cfA[i][kh], zf[j][kh], acc[i][j], 0, 0, 0);
    __builtin_amdgcn_s_setprio(0);
    __builtin_amdgcn_sched_barrier(0);
    __builtin_amdgcn_s_barrier();

    // ======== P2: quadrant (mf 2-3, nf 0-3); stage A1(t+1) ========
#pragma unroll
    for (int i = 0; i < 2; ++i) {
      cfB[i][0] = *reinterpret_cast<const bf16x8*>(Bb + (2 + i) * 2048 + fo0);
      cfB[i][1] = *reinterpret_cast<const bf16x8*>(Bb + (2 + i) * 2048 + fo1);
    }
    if (t + 1 < KT) STAGE(az1, t + 1, nbuf * 65536 + 16384);
    __builtin_amdgcn_sched_barrier(0);
    __builtin_amdgcn_s_barrier();
    __builtin_amdgcn_s_setprio(1);
#pragma unroll
    for (int kh = 0; kh < 2; ++kh)
#pragma unroll
      for (int i = 0; i < 2; ++i)
#pragma unroll
        for (int j = 0; j < 4; ++j)
          acc[2 + i][j] = __builtin_amdgcn_mfma_f32_16x16x32_bf16(cfB[i][kh], zf[j][kh], acc[2 + i][j], 0, 0, 0);
    __builtin_amdgcn_s_setprio(0);
    __builtin_amdgcn_sched_barrier(0);
    __builtin_amdgcn_s_barrier();

    // ======== P3: quadrant (mf 2-3, nf 4-7); stage B0(t+2) into current buf ========
#pragma unroll
    for (int j = 0; j < 4; ++j) {
      zf[j][0] = *reinterpret_cast<const bf16x8*>(Ab + (4 + j) * 2048 + fo0);
      zf[j][1] = *reinterpret_cast<const bf16x8*>(Ab + (4 + j) * 2048 + fo1);
    }
    if (t + 2 < KT) STAGE(ac0, t + 2, buf * 65536 + 32768);
    __builtin_amdgcn_sched_barrier(0);
    __builtin_amdgcn_s_barrier();
    __builtin_amdgcn_s_setprio(1);
#pragma unroll
    for (int kh = 0; kh < 2; ++kh)
#pragma unroll
      for (int i = 0; i < 2; ++i)
#pragma unroll
        for (int j = 0; j < 4; ++j)
          acc[2 + i][4 + j] = __builtin_amdgcn_mfma_f32_16x16x32_bf16(cfB[i][kh], zf[j][kh], acc[2 + i][4 + j], 0, 0, 0);
    __builtin_amdgcn_s_setprio(0);
    __builtin_amdgcn_sched_barrier(0);
    __builtin_amdgcn_s_barrier();

    // ======== P4: quadrant (mf 0-1, nf 4-7); stage B1(t+2); counted vmcnt ========
    if (t + 2 < KT) STAGE(ac1, t + 2, buf * 65536 + 49152);
    if (t < KT - 2) { asm volatile("s_waitcnt vmcnt(4)" ::: "memory"); }
    else            { asm volatile("s_waitcnt vmcnt(0)" ::: "memory"); }
    __builtin_amdgcn_sched_barrier(0);
    __builtin_amdgcn_s_barrier();
    __builtin_amdgcn_s_setprio(1);
#pragma unroll
    for (int kh = 0; kh < 2; ++kh)
#pragma unroll
      for (int i = 0; i < 2; ++i)
#pragma unroll
        for (int j = 0; j < 4; ++j)
          acc[i][4 + j] = __builtin_amdgcn_mfma_f32_16x16x32_bf16(cfA[i][kh], zf[j][kh], acc[i][4 + j], 0, 0, 0);
    __builtin_amdgcn_s_setprio(0);
    __builtin_amdgcn_sched_barrier(0);
    __builtin_amdgcn_s_barrier();
  }

  // ---- epilogue: per-row slice min key + candidate bitmap (contention-free) ----
  const int czero = col0 + wn * 64;
  const int zzero = row0 + wm * 128;
  const int slice = bn * 4 + wn;          // [0,128)
  float cnv[4][4];
#pragma unroll
  for (int i = 0; i < 4; ++i) {
    const float4 c4 = *reinterpret_cast<const float4*>(cnorm + czero + i * 16 + lg * 4);
    cnv[i][0] = c4.x; cnv[i][1] = c4.y; cnv[i][2] = c4.z; cnv[i][3] = c4.w;
  }
#pragma unroll
  for (int j = 0; j < 8; ++j) {
    const int row = zzero + j * 16 + lr;
    int qv[16];
    unsigned kmin = 0xffffffffu;
#pragma unroll
    for (int i = 0; i < 4; ++i)
#pragma unroll
      for (int reg = 0; reg < 4; ++reg) {
        const int col = czero + i * 16 + lg * 4 + reg;
        const int qb = qbias(cnv[i][reg] - 2.0f * acc[i][j][reg]);
        qv[i * 4 + reg] = qb;
        const unsigned key = ((unsigned)qb << 13) | (unsigned)col;
        kmin = key < kmin ? key : kmin;
      }
    {  // min across the 4 lg lanes holding this row
      unsigned o = (unsigned)__shfl_xor((int)kmin, 16, 64);
      kmin = o < kmin ? o : kmin;
      o = (unsigned)__shfl_xor((int)kmin, 32, 64);
      kmin = o < kmin ? o : kmin;
    }
    const int thr = (int)(kmin >> 13) + MARGIN_Q;
    unsigned mlo = 0, mhi = 0;
#pragma unroll
    for (int i = 0; i < 4; ++i) {
      unsigned nib = 0;
#pragma unroll
      for (int reg = 0; reg < 4; ++reg)
        if (qv[i * 4 + reg] <= thr) nib |= 1u << reg;
      const int sh = i * 16 + lg * 4;     // bit position of this lane's nibble
      if (i < 2) mlo |= nib << sh;
      else       mhi |= nib << (sh - 32);
    }
    mlo |= (unsigned)__shfl_xor((int)mlo, 16, 64);
    mlo |= (unsigned)__shfl_xor((int)mlo, 32, 64);
    mhi |= (unsigned)__shfl_xor((int)mhi, 16, 64);
    mhi |= (unsigned)__shfl_xor((int)mhi, 32, 64);
    if (lg == 0) {   // 16 lanes, consecutive rows -> coalesced in [slice][row] layout
      keys[(size_t)slice * RDIM + row] = kmin;
      masks[(size_t)slice * RDIM + row] = ((unsigned long long)mhi << 32) | (unsigned long long)mlo;
    }
  }
}

// ============ per-row: global min over 128 slice keys, gather candidates, exact refine ============
__global__ __launch_bounds__(64)
void collect_refine_kernel(const unsigned* __restrict__ keys,
                           const unsigned long long* __restrict__ masks,
                           const int* __restrict__ prev, const float* __restrict__ adj,
                           const float* __restrict__ gw_real, const float* __restrict__ gw_imag,
                           const float* __restrict__ codebook,
                           const float* __restrict__ znorm, const float* __restrict__ cnorm,
                           float* __restrict__ out, float* __restrict__ minfinal,
                           int* __restrict__ idxfinal) {
  __shared__ int s_list[MAXCAND];
  __shared__ int s_cnt;
  const int row = blockIdx.x;
  const int t = threadIdx.x;   // 64
  if (t == 0) s_cnt = 0;
  __syncthreads();
  const unsigned k0 = keys[(size_t)(2 * t) * RDIM + row];
  const unsigned k1 = keys[(size_t)(2 * t + 1) * RDIM + row];
  unsigned kmin = k0 < k1 ? k0 : k1;
#pragma unroll
  for (int m = 1; m < 64; m <<= 1) {
    const unsigned o = (unsigned)__shfl_xor((int)kmin, m, 64);
    kmin = o < kmin ? o : kmin;
  }
  const int qmin_b = (int)(kmin >> 13);
  const int winner = (int)(kmin & 8191u);
  const int thr = qmin_b + MARGIN_Q;
  // gather candidates from active slices (superset of global-margin set)
#pragma unroll
  for (int s2 = 0; s2 < 2; ++s2) {
    const int s = 2 * t + s2;
    const unsigned key = s2 ? k1 : k0;
    if ((int)(key >> 13) <= thr) {
      unsigned long long m = masks[(size_t)s * RDIM + row];
      while (m) {
        const int b = __builtin_ctzll(m);
        m &= m - 1;
        const int pos = atomicAdd(&s_cnt, 1);
        if (pos < MAXCAND) s_list[pos] = s * 64 + b;
      }
    }
  }
  __syncthreads();
  const int cnt = (s_cnt < MAXCAND) ? s_cnt : MAXCAND;
  if (cnt <= 1) {
    if (t == 0) {
      const int p = prev[row];
      const float bias = 0.8f / (1.0f + expf(-adj[(size_t)p * NDIM + winner]));
      out[OFF_IDX + row] = (float)winner;
      idxfinal[row] = winner;
      minfinal[row] = znorm[row] + (float)(qmin_b - 32768) * (1.0f / QSCALE) - bias;
    }
    return;
  }
  // exact fp32 biased lex-min over the candidates (whole wave per candidate)
  const int base = t * 16;
  const float* zp = (base < LDIM) ? gw_real + (size_t)row * LDIM + base
                                  : gw_imag + (size_t)row * LDIM + (base - LDIM);
  float z[16];
#pragma unroll
  for (int c = 0; c < 4; ++c) {
    const float4 zv = reinterpret_cast<const float4*>(zp)[c];
    z[c*4+0] = zv.x; z[c*4+1] = zv.y; z[c*4+2] = zv.z; z[c*4+3] = zv.w;
  }
  const float zn = znorm[row];
  const int p = prev[row];
  float bestd = FLT_BIG;
  int besti = 0x7fffffff;
  for (int j = 0; j < cnt; ++j) {
    const int idx = s_list[j];
    const float* cp = codebook + (size_t)idx * DDIM + base;
    float dot = 0.f;
#pragma unroll
    for (int c = 0; c < 4; ++c) {
      const float4 cv = reinterpret_cast<const float4*>(cp)[c];
      dot += z[c*4+0]*cv.x + z[c*4+1]*cv.y + z[c*4+2]*cv.z + z[c*4+3]*cv.w;
    }
    for (int m = 1; m < 64; m <<= 1) dot += __shfl_xor(dot, m, 64);
    const float d = zn + cnorm[idx] - 2.0f * dot
                  - 0.8f / (1.0f + expf(-adj[(size_t)p * NDIM + idx]));
    if (d < bestd || (d == bestd && idx < besti)) { bestd = d; besti = idx; }
  }
  if (t == 0) {
    out[OFF_IDX + row] = (float)besti;
    minfinal[row] = bestd;
    idxfinal[row] = besti;
  }
}

// ============ SHARED EPILOGUE (wave-reduce) ============

__global__ __launch_bounds__(256)
void epilogue_kernel(const float* __restrict__ gw_real, const float* __restrict__ gw_imag,
                     const float* __restrict__ codebook,
                     const float* __restrict__ sal_w, const float* __restrict__ sal_b,
                     const float* __restrict__ conf_w, const float* __restrict__ conf_b,
                     const float* __restrict__ minfinal, const int* __restrict__ idxfinal,
                     float* __restrict__ out, float* __restrict__ rowloss) {
  __shared__ float s1[4], s2[4], s3[4];
  const int row = blockIdx.x;
  const int t = threadIdx.x;
  const int w = t >> 6, l = t & 63;
  const int k = t << 2;
  const int idx = idxfinal[row];
  const float4 qv = *reinterpret_cast<const float4*>(codebook + (size_t)idx * DDIM + k);
  float4 z;
  if (k < LDIM) z = *reinterpret_cast<const float4*>(gw_real + (size_t)row * LDIM + k);
  else          z = *reinterpret_cast<const float4*>(gw_imag + (size_t)row * LDIM + (k - LDIM));
  const float dx = qv.x - z.x, dy = qv.y - z.y, dz = qv.z - z.z, dw = qv.w - z.w;
  float4 st;
  st.x = z.x + dx; st.y = z.y + dy; st.z = z.z + dz; st.w = z.w + dw;
  float* dst = (k < LDIM) ? (out + OFF_REAL + (size_t)row * LDIM + k)
                          : (out + OFF_IMAG + (size_t)row * LDIM + (k - LDIM));
  *reinterpret_cast<float4*>(dst) = st;
  const float4 sw = *reinterpret_cast<const float4*>(sal_w + k);
  const float4 cw = *reinterpret_cast<const float4*>(conf_w + k);
  float r1 = st.x*sw.x + st.y*sw.y + st.z*sw.z + st.w*sw.w;
  float r2 = st.x*cw.x + st.y*cw.y + st.z*cw.z + st.w*cw.w;
  float r3 = dx*dx + dy*dy + dz*dz + dw*dw;
#pragma unroll
  for (int m = 1; m < 64; m <<= 1) {
    r1 += __shfl_xor(r1, m, 64);
    r2 += __shfl_xor(r2, m, 64);
    r3 += __shfl_xor(r3, m, 64);
  }
  if (l == 0) { s1[w] = r1; s2[w] = r2; s3[w] = r3; }
  __syncthreads();
  if (t == 0) {
    const float t1 = s1[0] + s1[1] + s1[2] + s1[3];
    const float t2 = s2[0] + s2[1] + s2[2] + s2[3];
    const float t3 = s3[0] + s3[1] + s3[2] + s3[3];
    out[OFF_SAL + row]  = t1 + sal_b[0] + 0.1f * (-minfinal[row]);
    out[OFF_CONF + row] = 1.0f / (1.0f + expf(-(t2 + conf_b[0])));
    rowloss[row] = t3;
  }
}

__global__ __launch_bounds__(256)
void loss_kernel(const float* __restrict__ rowloss, float* __restrict__ out) {
  const int t = threadIdx.x;
  float s = 0.f;
  for (int i = t; i < RDIM; i += 256) s += rowloss[i];
  __shared__ float red[256];
  red[t] = s;
  __syncthreads();
  for (int st = 128; st > 0; st >>= 1) {
    if (t < st) red[t] += red[t + st];
    __syncthreads();
  }
  if (t == 0) {
    const float m = red[0] / (float)((size_t)RDIM * DDIM);
    out[OFF_LOSS] = m + 0.01f * m;
  }
}

// ============ FALLBACK (round-1 fp32 path) ============

__global__ __launch_bounds__(256)
void norms_kernel(const float* __restrict__ gw_real, const float* __restrict__ gw_imag,
                  const float* __restrict__ codebook,
                  float* __restrict__ znorm, float* __restrict__ cnorm) {
  const int id = blockIdx.x;
  const int t = threadIdx.x;
  float s;
  if (id < RDIM) {
    const float4* zr = reinterpret_cast<const float4*>(gw_real + (size_t)id * LDIM);
    const float4* zi = reinterpret_cast<const float4*>(gw_imag + (size_t)id * LDIM);
    const float4 v = (t < 128) ? zr[t] : zi[t - 128];
    s = v.x*v.x + v.y*v.y + v.z*v.z + v.w*v.w;
  } else {
    const float4* c = reinterpret_cast<const float4*>(codebook + (size_t)(id - RDIM) * DDIM);
    const float4 v = c[t];
    s = v.x*v.x + v.y*v.y + v.z*v.z + v.w*v.w;
  }
  __shared__ float red[256];
  red[t] = s;
  __syncthreads();
  for (int st = 128; st > 0; st >>= 1) {
    if (t < st) red[t] += red[t + st];
    __syncthreads();
  }
  if (t == 0) {
    if (id < RDIM) znorm[id] = red[0];
    else           cnorm[id - RDIM] = red[0];
  }
}

__global__ __launch_bounds__(256)
void dist_kernel(const float* __restrict__ gw_real, const float* __restrict__ gw_imag,
                 const float* __restrict__ codebook, const int* __restrict__ prev,
                 const float* __restrict__ adj, const float* __restrict__ znorm,
                 const float* __restrict__ cnorm,
                 float* __restrict__ ws_min, int* __restrict__ ws_idx) {
  __shared__ float As[16][64];
  __shared__ float Bs[16][64];
  __shared__ int prevs[64];
  const int bm = blockIdx.x, bn = blockIdx.y;
  const int row0 = bm * 64, col0 = bn * 64;
  const int tid = threadIdx.x;
  const int tx = tid & 15, ty = tid >> 4;
  if (tid < 64) prevs[tid] = prev[row0 + tid];
  const int lm = tid >> 2;
  const int lk = (tid & 3) << 2;
  const int arow = row0 + lm;
  const int brow = col0 + lm;
  float acc[4][4] = {{0.f,0.f,0.f,0.f},{0.f,0.f,0.f,0.f},{0.f,0.f,0.f,0.f},{0.f,0.f,0.f,0.f}};
  for (int kk = 0; kk < DDIM; kk += 16) {
    const int k = kk + lk;
    float4 a, b;
    if (k < LDIM) a = *reinterpret_cast<const float4*>(gw_real + (size_t)arow * LDIM + k);
    else          a = *reinterpret_cast<const float4*>(gw_imag + (size_t)arow * LDIM + (k - LDIM));
    b = *reinterpret_cast<const float4*>(codebook + (size_t)brow * DDIM + k);
    __syncthreads();
    As[lk+0][lm]=a.x; As[lk+1][lm]=a.y; As[lk+2][lm]=a.z; As[lk+3][lm]=a.w;
    Bs[lk+0][lm]=b.x; Bs[lk+1][lm]=b.y; Bs[lk+2][lm]=b.z; Bs[lk+3][lm]=b.w;
    __syncthreads();
#pragma unroll
    for (int k2 = 0; k2 < 16; ++k2) {
      const float4 a4 = *reinterpret_cast<const float4*>(&As[k2][ty << 2]);
      const float4 b4 = *reinterpret_cast<const float4*>(&Bs[k2][tx << 2]);
      const float av[4] = {a4.x, a4.y, a4.z, a4.w};
      const float bv[4] = {b4.x, b4.y, b4.z, b4.w};
#pragma unroll
      for (int i = 0; i < 4; ++i)
#pragma unroll
        for (int j = 0; j < 4; ++j)
          acc[i][j] = fmaf(av[i], bv[j], acc[i][j]);
    }
  }
  const float4 cn4 = *reinterpret_cast<const float4*>(cnorm + col0 + (tx << 2));
  const float cnv[4] = {cn4.x, cn4.y, cn4.z, cn4.w};
#pragma unroll
  for (int i = 0; i < 4; ++i) {
    const int rsub = (ty << 2) + i;
    const int row = row0 + rsub;
    const float zn = znorm[row];
    const int p = prevs[rsub];
    const float4 ad4 = *reinterpret_cast<const float4*>(adj + (size_t)p * NDIM + col0 + (tx << 2));
    const float adv[4] = {ad4.x, ad4.y, ad4.z, ad4.w};
    float bv = FLT_BIG;
    int bi = -1;
#pragma unroll
    for (int j = 0; j < 4; ++j) {
      const float bias = 0.8f * (1.0f / (1.0f + expf(-adv[j])));
      const float dv = (zn + cnv[j]) - 2.0f * acc[i][j] - bias;
      const int col = col0 + (tx << 2) + j;
      if (dv < bv) { bv = dv; bi = col; }
    }
    for (int m = 1; m < 16; m <<= 1) {
      const float ov = __shfl_xor(bv, m, 64);
      const int   oi = __shfl_xor(bi, m, 64);
      if (ov < bv || (ov == bv && oi < bi)) { bv = ov; bi = oi; }
    }
    if (tx == 0) {
      ws_min[(size_t)row * 128 + bn] = bv;
      ws_idx[(size_t)row * 128 + bn] = bi;
    }
  }
}

__global__ __launch_bounds__(128)
void argmin_reduce(const float* __restrict__ ws_min, const int* __restrict__ ws_idx,
                   float* __restrict__ out, float* __restrict__ minfinal,
                   int* __restrict__ idxfinal) {
  const int row = blockIdx.x;
  const int t = threadIdx.x;
  __shared__ float sv[128];
  __shared__ int   si[128];
  sv[t] = ws_min[(size_t)row * 128 + t];
  si[t] = ws_idx[(size_t)row * 128 + t];
  __syncthreads();
  for (int s = 64; s > 0; s >>= 1) {
    if (t < s) {
      const float ov = sv[t + s];
      const int   oi = si[t + s];
      if (ov < sv[t] || (ov == sv[t] && oi < si[t])) { sv[t] = ov; si[t] = oi; }
    }
    __syncthreads();
  }
  if (t == 0) {
    out[OFF_IDX + row] = (float)si[0];
    minfinal[row] = sv[0];
    idxfinal[row] = si[0];
  }
}

// ============ HOST ============

extern "C" void kernel_launch(void* const* d_in, const int* in_sizes, int n_in,
                              void* d_out, int out_size, void* d_ws, size_t ws_size,
                              hipStream_t stream) {
  const float* gw_real  = (const float*)d_in[0];
  const float* gw_imag  = (const float*)d_in[1];
  const int*   prev     = (const int*)d_in[2];
  const float* codebook = (const float*)d_in[3];
  const float* adj      = (const float*)d_in[4];
  const float* sal_w    = (const float*)d_in[5];
  const float* sal_b    = (const float*)d_in[6];
  const float* conf_w   = (const float*)d_in[7];
  const float* conf_b   = (const float*)d_in[8];
  float* out = (float*)d_out;
  char* ws = (char*)d_ws;

  const size_t matsz  = (size_t)RDIM * DDIM;             // bf16 elements per matrix
  const size_t nslice = (size_t)RDIM * 128;              // (row, 64-col-slice) cells
  size_t need = 2 * matsz * 2                            // zh, ch (bf16)
              + nslice * 4 + nslice * 8                  // keys, masks
              + 5 * (size_t)RDIM * 4 + 4096;             // znorm,cnorm,minfinal,idxfinal,rowloss

  if (ws_size >= need) {
    unsigned short* zh = (unsigned short*)ws;
    unsigned short* chh = zh + matsz;
    unsigned* keys = (unsigned*)(chh + matsz);
    unsigned long long* masks = (unsigned long long*)(keys + nslice);
    float* znorm    = (float*)(masks + nslice);
    float* cnorm    = znorm + RDIM;
    float* minfinal = cnorm + NDIM;
    int*   idxfinal = (int*)(minfinal + RDIM);
    float* rowloss  = (float*)(idxfinal + RDIM);

    split_norms_kernel<<<(RDIM + NDIM) / 4, 256, 0, stream>>>(gw_real, gw_imag, codebook,
                                                              zh, chh, znorm, cnorm);
    dist_mfma_kernel<<<1024, 512, 0, stream>>>(zh, chh, cnorm, keys, masks);
    collect_refine_kernel<<<RDIM, 64, 0, stream>>>(keys, masks, prev, adj,
                                                   gw_real, gw_imag, codebook,
                                                   znorm, cnorm, out, minfinal, idxfinal);
    epilogue_kernel<<<RDIM, 256, 0, stream>>>(gw_real, gw_imag, codebook, sal_w, sal_b,
                                              conf_w, conf_b, minfinal, idxfinal, out, rowloss);
    loss_kernel<<<1, 256, 0, stream>>>(rowloss, out);
  } else {
    float* ws_min   = (float*)ws;
    int*   ws_idx   = (int*)(ws + (size_t)RDIM * 128 * 4);
    float* znorm    = (float*)(ws + (size_t)RDIM * 128 * 8);
    float* cnorm    = znorm + RDIM;
    float* minfinal = cnorm + NDIM;
    int*   idxfinal = (int*)(minfinal + RDIM);
    float* rowloss  = (float*)(idxfinal + RDIM);

    norms_kernel<<<RDIM + NDIM, 256, 0, stream>>>(gw_real, gw_imag, codebook, znorm, cnorm);
    dist_kernel<<<dim3(RDIM / 64, NDIM / 64), 256, 0, stream>>>(
        gw_real, gw_imag, codebook, prev, adj, znorm, cnorm, ws_min, ws_idx);
    argmin_reduce<<<RDIM, 128, 0, stream>>>(ws_min, ws_idx, out, minfinal, idxfinal);
    epilogue_kernel<<<RDIM, 256, 0, stream>>>(gw_real, gw_imag, codebook, sal_w, sal_b,
                                              conf_w, conf_b, minfinal, idxfinal, out, rowloss);
    loss_kernel<<<1, 256, 0, stream>>>(rowloss, out);
  }
}

// Round 12
// 190.386 us; speedup vs baseline: 1.9569x; 1.0257x over previous
//
#include <hip/hip_runtime.h>
#include <math.h>

#define RDIM 8192   // B*S
#define DDIM 1024   // 2*L
#define NDIM 8192
#define LDIM 512
#define KT 16       // K-steps of 64 over K=1024

#define OFF_REAL 0
#define OFF_IMAG 4194304
#define OFF_SAL  8388608
#define OFF_CONF 8396800
#define OFF_LOSS 8404992
#define OFF_IDX  8404993

#define MAXCAND 64
#define MARGIN_Q 76        // 1.1875 units of d: 0.8 bias range + bf16 pair err + quant
#define QSCALE 64.0f
#define FLT_BIG 3.4e38f

typedef __attribute__((ext_vector_type(8))) short bf16x8;
typedef __attribute__((ext_vector_type(8))) short short8v;
typedef __attribute__((ext_vector_type(4))) float f32x4;

__device__ __forceinline__ unsigned short f2bf(float x) {
  unsigned u = __builtin_bit_cast(unsigned, x);
  unsigned r = (u + 0x7fff + ((u >> 16) & 1)) >> 16;
  return (unsigned short)r;
}

__device__ __forceinline__ void load_lds16(const void* g, void* l) {
  __builtin_amdgcn_global_load_lds((const __attribute__((address_space(1))) void*)g,
                                   (__attribute__((address_space(3))) void*)l, 16, 0, 0);
}

// quantize to biased int in [1, 65535]
__device__ __forceinline__ int qbias(float s) {
  int qi = __float2int_rn(s * QSCALE);
  qi = qi > 32767 ? 32767 : (qi < -32767 ? -32767 : qi);
  return qi + 32768;
}

// ============ bf16 cast + exact fp32 norms (wave-per-row, shuffle-only) ============
__global__ __launch_bounds__(256)
void split_norms_kernel(const float* __restrict__ gw_real, const float* __restrict__ gw_imag,
                        const float* __restrict__ codebook,
                        unsigned short* __restrict__ zh, unsigned short* __restrict__ ch,
                        float* __restrict__ znorm, float* __restrict__ cnorm) {
  const int w = threadIdx.x >> 6, l = threadIdx.x & 63;
  const int id = blockIdx.x * 4 + w;     // [0, 16384)
  const float* src;
  unsigned short* dst;
  float* nrm;
  int row;
  if (id < RDIM) {
    row = id; dst = zh; nrm = znorm;
    src = (l < 32) ? gw_real + (size_t)row * LDIM + l * 16
                   : gw_imag + (size_t)row * LDIM + (l - 32) * 16;
  } else {
    row = id - RDIM; dst = ch; nrm = cnorm;
    src = codebook + (size_t)row * DDIM + l * 16;
  }
  float f[16];
#pragma unroll
  for (int i = 0; i < 4; ++i) {
    const float4 v = reinterpret_cast<const float4*>(src)[i];
    f[i*4+0] = v.x; f[i*4+1] = v.y; f[i*4+2] = v.z; f[i*4+3] = v.w;
  }
  short8v h0, h1;
  float s = 0.f;
#pragma unroll
  for (int i = 0; i < 8; ++i) { h0[i] = (short)f2bf(f[i]);     s += f[i] * f[i]; }
#pragma unroll
  for (int i = 0; i < 8; ++i) { h1[i] = (short)f2bf(f[8 + i]); s += f[8+i] * f[8+i]; }
  unsigned short* dp = dst + (size_t)row * DDIM + l * 16;
  *reinterpret_cast<short8v*>(dp)     = h0;
  *reinterpret_cast<short8v*>(dp + 8) = h1;
#pragma unroll
  for (int m = 1; m < 64; m <<= 1) s += __shfl_xor(s, m, 64);
  if (l == 0) nrm[row] = s;
}

// ============ 256x256 tile, BK=64, 8-wave 4-phase bf16 GEMM (r11, sched_barrier pins removed) ============
#define STAGE(basep, kt, ldsbyte) do {                                        \
    load_lds16((basep) + eo1 + (kt) * 64, L + (ldsbyte) + wid * 1024);        \
    load_lds16((basep) + eo2 + (kt) * 64, L + (ldsbyte) + 8192 + wid * 1024); \
  } while (0)

__global__ __launch_bounds__(512)
void dist_mfma_kernel(const unsigned short* __restrict__ zh, const unsigned short* __restrict__ ch,
                      const float* __restrict__ cnorm,
                      unsigned* __restrict__ keys, unsigned long long* __restrict__ masks) {
  __shared__ unsigned short ldsbuf[65536];   // 128 KB: [buf][A 32K | B 32K]
  char* const L = (char*)ldsbuf;

  // XCD-aware swizzle (1024 blocks = 8 XCDs x 128, bijective)
  const int sidx = (int)blockIdx.x;
  const int sw = (sidx & 7) * 128 + (sidx >> 3);
  const int bm = sw >> 5, bn = sw & 31;
  const int row0 = bm * 256, col0 = bn * 256;

  const int tid = threadIdx.x;
  const int wid = tid >> 6, l = tid & 63;
  const int wm = wid >> 2, wn = wid & 3;       // 2 x 4 wave grid
  const int lr = l & 15, lg = l >> 4;

  // ---- staging geometry: half-tile = 128 rows x 64 cols bf16 = 1024 chunks of 16B
  const int p1 = tid, p2 = tid + 512;
  const int r1 = p1 >> 3, c1 = (p1 & 7) ^ (r1 & 7);
  const int r2 = p2 >> 3, c2 = (p2 & 7) ^ (r2 & 7);
  const int eo1 = r1 * DDIM + c1 * 8;
  const int eo2 = r2 * DDIM + c2 * 8;
  const unsigned short* const az0 = zh + (size_t)row0 * DDIM;
  const unsigned short* const az1 = zh + (size_t)(row0 + 128) * DDIM;
  const unsigned short* const ac0 = ch + (size_t)col0 * DDIM;
  const unsigned short* const ac1 = ch + (size_t)(col0 + 128) * DDIM;

  // ---- fragment read offsets (row = base + lr, chunk' = (kh*4+lg) ^ (lr&7))
  const int fo0 = lr * 128 + ((lg ^ (lr & 7)) << 4);
  const int fo1 = fo0 ^ 64;

  f32x4 acc[4][8];
#pragma unroll
  for (int i = 0; i < 4; ++i)
#pragma unroll
    for (int j = 0; j < 8; ++j)
      acc[i][j] = (f32x4){0.f, 0.f, 0.f, 0.f};

  bf16x8 cfA[2][2], cfB[2][2], zf[4][2];

  // ---- prologue: tile0 (A+B) into buf0, B(1) into buf1; A(1) staged inside loop t=0
  STAGE(az0, 0, 0);
  STAGE(az1, 0, 16384);
  STAGE(ac0, 0, 32768);
  STAGE(ac1, 0, 49152);
  STAGE(ac0, 1, 98304);
  STAGE(ac1, 1, 114688);
  asm volatile("s_waitcnt vmcnt(4)" ::: "memory");   // tile0 landed; B(1) may fly
  __builtin_amdgcn_s_barrier();

  for (int t = 0; t < KT; ++t) {
    const int buf = t & 1, nbuf = buf ^ 1;
    const char* const Ab = L + buf * 65536 + wm * 16384;          // wave's z-half
    const char* const Bb = L + buf * 65536 + 32768 + wn * 8192;   // wave's c-64-block

    // ======== P1: quadrant (mf 0-1, nf 0-3); stage A0(t+1) ========
#pragma unroll
    for (int i = 0; i < 2; ++i) {
      cfA[i][0] = *reinterpret_cast<const bf16x8*>(Bb + i * 2048 + fo0);
      cfA[i][1] = *reinterpret_cast<const bf16x8*>(Bb + i * 2048 + fo1);
    }
#pragma unroll
    for (int j = 0; j < 4; ++j) {
      zf[j][0] = *reinterpret_cast<const bf16x8*>(Ab + j * 2048 + fo0);
      zf[j][1] = *reinterpret_cast<const bf16x8*>(Ab + j * 2048 + fo1);
    }
    if (t + 1 < KT) STAGE(az0, t + 1, nbuf * 65536);
    __builtin_amdgcn_s_barrier();
    __builtin_amdgcn_s_setprio(1);
#pragma unroll
    for (int kh = 0; kh < 2; ++kh)
#pragma unroll
      for (int i = 0; i < 2; ++i)
#pragma unroll
        for (int j = 0; j < 4; ++j)
          acc[i][j] = __builtin_amdgcn_mfma_f32_16x16x32_bf16(cfA[i][kh], zf[j][kh], acc[i][j], 0, 0, 0);
    __builtin_amdgcn_s_setprio(0);
    __builtin_amdgcn_s_barrier();

    // ======== P2: quadrant (mf 2-3, nf 0-3); stage A1(t+1) ========
#pragma unroll
    for (int i = 0; i < 2; ++i) {
      cfB[i][0] = *reinterpret_cast<const bf16x8*>(Bb + (2 + i) * 2048 + fo0);
      cfB[i][1] = *reinterpret_cast<const bf16x8*>(Bb + (2 + i) * 2048 + fo1);
    }
    if (t + 1 < KT) STAGE(az1, t + 1, nbuf * 65536 + 16384);
    __builtin_amdgcn_s_barrier();
    __builtin_amdgcn_s_setprio(1);
#pragma unroll
    for (int kh = 0; kh < 2; ++kh)
#pragma unroll
      for (int i = 0; i < 2; ++i)
#pragma unroll
        for (int j = 0; j < 4; ++j)
          acc[2 + i][j] = __builtin_amdgcn_mfma_f32_16x16x32_bf16(cfB[i][kh], zf[j][kh], acc[2 + i][j], 0, 0, 0);
    __builtin_amdgcn_s_setprio(0);
    __builtin_amdgcn_s_barrier();

    // ======== P3: quadrant (mf 2-3, nf 4-7); stage B0(t+2) into current buf ========
#pragma unroll
    for (int j = 0; j < 4; ++j) {
      zf[j][0] = *reinterpret_cast<const bf16x8*>(Ab + (4 + j) * 2048 + fo0);
      zf[j][1] = *reinterpret_cast<const bf16x8*>(Ab + (4 + j) * 2048 + fo1);
    }
    if (t + 2 < KT) STAGE(ac0, t + 2, buf * 65536 + 32768);
    __builtin_amdgcn_s_barrier();
    __builtin_amdgcn_s_setprio(1);
#pragma unroll
    for (int kh = 0; kh < 2; ++kh)
#pragma unroll
      for (int i = 0; i < 2; ++i)
#pragma unroll
        for (int j = 0; j < 4; ++j)
          acc[2 + i][4 + j] = __builtin_amdgcn_mfma_f32_16x16x32_bf16(cfB[i][kh], zf[j][kh], acc[2 + i][4 + j], 0, 0, 0);
    __builtin_amdgcn_s_setprio(0);
    __builtin_amdgcn_s_barrier();

    // ======== P4: quadrant (mf 0-1, nf 4-7); stage B1(t+2); counted vmcnt ========
    if (t + 2 < KT) STAGE(ac1, t + 2, buf * 65536 + 49152);
    if (t < KT - 2) { asm volatile("s_waitcnt vmcnt(4)" ::: "memory"); }
    else            { asm volatile("s_waitcnt vmcnt(0)" ::: "memory"); }
    __builtin_amdgcn_s_barrier();
    __builtin_amdgcn_s_setprio(1);
#pragma unroll
    for (int kh = 0; kh < 2; ++kh)
#pragma unroll
      for (int i = 0; i < 2; ++i)
#pragma unroll
        for (int j = 0; j < 4; ++j)
          acc[i][4 + j] = __builtin_amdgcn_mfma_f32_16x16x32_bf16(cfA[i][kh], zf[j][kh], acc[i][4 + j], 0, 0, 0);
    __builtin_amdgcn_s_setprio(0);
    __builtin_amdgcn_s_barrier();
  }

  // ---- epilogue: per-row slice min key + candidate bitmap (contention-free) ----
  const int czero = col0 + wn * 64;
  const int zzero = row0 + wm * 128;
  const int slice = bn * 4 + wn;          // [0,128)
  float cnv[4][4];
#pragma unroll
  for (int i = 0; i < 4; ++i) {
    const float4 c4 = *reinterpret_cast<const float4*>(cnorm + czero + i * 16 + lg * 4);
    cnv[i][0] = c4.x; cnv[i][1] = c4.y; cnv[i][2] = c4.z; cnv[i][3] = c4.w;
  }
#pragma unroll
  for (int j = 0; j < 8; ++j) {
    const int row = zzero + j * 16 + lr;
    int qv[16];
    unsigned kmin = 0xffffffffu;
#pragma unroll
    for (int i = 0; i < 4; ++i)
#pragma unroll
      for (int reg = 0; reg < 4; ++reg) {
        const int col = czero + i * 16 + lg * 4 + reg;
        const int qb = qbias(cnv[i][reg] - 2.0f * acc[i][j][reg]);
        qv[i * 4 + reg] = qb;
        const unsigned key = ((unsigned)qb << 13) | (unsigned)col;
        kmin = key < kmin ? key : kmin;
      }
    {  // min across the 4 lg lanes holding this row
      unsigned o = (unsigned)__shfl_xor((int)kmin, 16, 64);
      kmin = o < kmin ? o : kmin;
      o = (unsigned)__shfl_xor((int)kmin, 32, 64);
      kmin = o < kmin ? o : kmin;
    }
    const int thr = (int)(kmin >> 13) + MARGIN_Q;
    unsigned mlo = 0, mhi = 0;
#pragma unroll
    for (int i = 0; i < 4; ++i) {
      unsigned nib = 0;
#pragma unroll
      for (int reg = 0; reg < 4; ++reg)
        if (qv[i * 4 + reg] <= thr) nib |= 1u << reg;
      const int sh = i * 16 + lg * 4;     // bit position of this lane's nibble
      if (i < 2) mlo |= nib << sh;
      else       mhi |= nib << (sh - 32);
    }
    mlo |= (unsigned)__shfl_xor((int)mlo, 16, 64);
    mlo |= (unsigned)__shfl_xor((int)mlo, 32, 64);
    mhi |= (unsigned)__shfl_xor((int)mhi, 16, 64);
    mhi |= (unsigned)__shfl_xor((int)mhi, 32, 64);
    if (lg == 0) {   // 16 lanes, consecutive rows -> coalesced in [slice][row] layout
      keys[(size_t)slice * RDIM + row] = kmin;
      masks[(size_t)slice * RDIM + row] = ((unsigned long long)mhi << 32) | (unsigned long long)mlo;
    }
  }
}

// ============ fused per-row tail: key-min -> bitmap gather -> refine -> final epilogue ============
__global__ __launch_bounds__(256)
void tail_kernel(const unsigned* __restrict__ keys, const unsigned long long* __restrict__ masks,
                 const int* __restrict__ prev, const float* __restrict__ adj,
                 const float* __restrict__ gw_real, const float* __restrict__ gw_imag,
                 const float* __restrict__ codebook,
                 const float* __restrict__ sal_w, const float* __restrict__ sal_b,
                 const float* __restrict__ conf_w, const float* __restrict__ conf_b,
                 const float* __restrict__ znorm, const float* __restrict__ cnorm,
                 float* __restrict__ out, float* __restrict__ rowloss) {
  __shared__ unsigned s_wmin[4];
  __shared__ int s_cnt;
  __shared__ int s_list[MAXCAND];
  __shared__ float s_bv[4], s_fd;
  __shared__ int   s_bi[4], s_fi;
  __shared__ float s1[4], s2[4], s3[4];
  const int row = blockIdx.x;
  const int t = threadIdx.x;   // 256
  const int w = t >> 6, l = t & 63;
  if (t == 0) s_cnt = 0;
  // ---- global min over 128 slice keys ----
  const unsigned k = (t < 128) ? keys[(size_t)t * RDIM + row] : 0xffffffffu;
  unsigned km = k;
#pragma unroll
  for (int m = 1; m < 64; m <<= 1) {
    const unsigned o = (unsigned)__shfl_xor((int)km, m, 64);
    km = o < km ? o : km;
  }
  if (l == 0) s_wmin[w] = km;
  __syncthreads();
  unsigned gk = s_wmin[0];
  gk = gk < s_wmin[1] ? gk : s_wmin[1];
  gk = gk < s_wmin[2] ? gk : s_wmin[2];
  gk = gk < s_wmin[3] ? gk : s_wmin[3];
  const int qmin_b = (int)(gk >> 13);
  const int winner = (int)(gk & 8191u);
  const int thr = qmin_b + MARGIN_Q;
  // ---- gather candidates from active slices ----
  if (t < 128 && (int)(k >> 13) <= thr) {
    unsigned long long m = masks[(size_t)t * RDIM + row];
    while (m) {
      const int b = __builtin_ctzll(m);
      m &= m - 1;
      const int pos = atomicAdd(&s_cnt, 1);
      if (pos < MAXCAND) s_list[pos] = t * 64 + b;
    }
  }
  __syncthreads();
  const int cnt = (s_cnt < MAXCAND) ? s_cnt : MAXCAND;
  const float zn = znorm[row];
  const int p = prev[row];
  if (cnt <= 1) {
    if (t == 0) {
      const float bias = 0.8f / (1.0f + expf(-adj[(size_t)p * NDIM + winner]));
      s_fi = winner;
      s_fd = zn + (float)(qmin_b - 32768) * (1.0f / QSCALE) - bias;
    }
  } else {
    // exact fp32 refine: 4 waves x strided candidates
    const int base = l * 16;
    const float* zp = (base < LDIM) ? gw_real + (size_t)row * LDIM + base
                                    : gw_imag + (size_t)row * LDIM + (base - LDIM);
    float z[16];
#pragma unroll
    for (int c = 0; c < 4; ++c) {
      const float4 zv = reinterpret_cast<const float4*>(zp)[c];
      z[c*4+0] = zv.x; z[c*4+1] = zv.y; z[c*4+2] = zv.z; z[c*4+3] = zv.w;
    }
    float bestd = FLT_BIG;
    int besti = 0x7fffffff;
    for (int j = w; j < cnt; j += 4) {
      const int idx = s_list[j];
      const float* cp = codebook + (size_t)idx * DDIM + base;
      float dot = 0.f;
#pragma unroll
      for (int c = 0; c < 4; ++c) {
        const float4 cv = reinterpret_cast<const float4*>(cp)[c];
        dot += z[c*4+0]*cv.x + z[c*4+1]*cv.y + z[c*4+2]*cv.z + z[c*4+3]*cv.w;
      }
      for (int m = 1; m < 64; m <<= 1) dot += __shfl_xor(dot, m, 64);
      const float d = zn + cnorm[idx] - 2.0f * dot
                    - 0.8f / (1.0f + expf(-adj[(size_t)p * NDIM + idx]));
      if (d < bestd || (d == bestd && idx < besti)) { bestd = d; besti = idx; }
    }
    if (l == 0) { s_bv[w] = bestd; s_bi[w] = besti; }
    __syncthreads();
    if (t == 0) {
      float bv = s_bv[0]; int bi = s_bi[0];
#pragma unroll
      for (int w2 = 1; w2 < 4; ++w2) {
        const float ov = s_bv[w2]; const int oi = s_bi[w2];
        if (ov < bv || (ov == bv && oi < bi)) { bv = ov; bi = oi; }
      }
      s_fd = bv; s_fi = bi;
    }
  }
  __syncthreads();
  const int idx = s_fi;
  const float dmin = s_fd;
  // ---- final epilogue: proposals, salience, confidence, rowloss ----
  const int k4 = t << 2;
  const float4 qv = *reinterpret_cast<const float4*>(codebook + (size_t)idx * DDIM + k4);
  float4 z4;
  if (k4 < LDIM) z4 = *reinterpret_cast<const float4*>(gw_real + (size_t)row * LDIM + k4);
  else           z4 = *reinterpret_cast<const float4*>(gw_imag + (size_t)row * LDIM + (k4 - LDIM));
  const float dx = qv.x - z4.x, dy = qv.y - z4.y, dz = qv.z - z4.z, dw = qv.w - z4.w;
  float4 st;
  st.x = z4.x + dx; st.y = z4.y + dy; st.z = z4.z + dz; st.w = z4.w + dw;
  float* dst = (k4 < LDIM) ? (out + OFF_REAL + (size_t)row * LDIM + k4)
                           : (out + OFF_IMAG + (size_t)row * LDIM + (k4 - LDIM));
  *reinterpret_cast<float4*>(dst) = st;
  const float4 sw4 = *reinterpret_cast<const float4*>(sal_w + k4);
  const float4 cw4 = *reinterpret_cast<const float4*>(conf_w + k4);
  float r1 = st.x*sw4.x + st.y*sw4.y + st.z*sw4.z + st.w*sw4.w;
  float r2 = st.x*cw4.x + st.y*cw4.y + st.z*cw4.z + st.w*cw4.w;
  float r3 = dx*dx + dy*dy + dz*dz + dw*dw;
#pragma unroll
  for (int m = 1; m < 64; m <<= 1) {
    r1 += __shfl_xor(r1, m, 64);
    r2 += __shfl_xor(r2, m, 64);
    r3 += __shfl_xor(r3, m, 64);
  }
  if (l == 0) { s1[w] = r1; s2[w] = r2; s3[w] = r3; }
  __syncthreads();
  if (t == 0) {
    const float t1 = s1[0] + s1[1] + s1[2] + s1[3];
    const float t2 = s2[0] + s2[1] + s2[2] + s2[3];
    const float t3 = s3[0] + s3[1] + s3[2] + s3[3];
    out[OFF_IDX + row] = (float)idx;
    out[OFF_SAL + row]  = t1 + sal_b[0] + 0.1f * (-dmin);
    out[OFF_CONF + row] = 1.0f / (1.0f + expf(-(t2 + conf_b[0])));
    rowloss[row] = t3;
  }
}

__global__ __launch_bounds__(256)
void loss_kernel(const float* __restrict__ rowloss, float* __restrict__ out) {
  const int t = threadIdx.x;
  float s = 0.f;
  for (int i = t; i < RDIM; i += 256) s += rowloss[i];
  __shared__ float red[256];
  red[t] = s;
  __syncthreads();
  for (int st = 128; st > 0; st >>= 1) {
    if (t < st) red[t] += red[t + st];
    __syncthreads();
  }
  if (t == 0) {
    const float m = red[0] / (float)((size_t)RDIM * DDIM);
    out[OFF_LOSS] = m + 0.01f * m;
  }
}

// ============ FALLBACK (round-1 fp32 path) ============

__global__ __launch_bounds__(256)
void norms_kernel(const float* __restrict__ gw_real, const float* __restrict__ gw_imag,
                  const float* __restrict__ codebook,
                  float* __restrict__ znorm, float* __restrict__ cnorm) {
  const int id = blockIdx.x;
  const int t = threadIdx.x;
  float s;
  if (id < RDIM) {
    const float4* zr = reinterpret_cast<const float4*>(gw_real + (size_t)id * LDIM);
    const float4* zi = reinterpret_cast<const float4*>(gw_imag + (size_t)id * LDIM);
    const float4 v = (t < 128) ? zr[t] : zi[t - 128];
    s = v.x*v.x + v.y*v.y + v.z*v.z + v.w*v.w;
  } else {
    const float4* c = reinterpret_cast<const float4*>(codebook + (size_t)(id - RDIM) * DDIM);
    const float4 v = c[t];
    s = v.x*v.x + v.y*v.y + v.z*v.z + v.w*v.w;
  }
  __shared__ float red[256];
  red[t] = s;
  __syncthreads();
  for (int st = 128; st > 0; st >>= 1) {
    if (t < st) red[t] += red[t + st];
    __syncthreads();
  }
  if (t == 0) {
    if (id < RDIM) znorm[id] = red[0];
    else           cnorm[id - RDIM] = red[0];
  }
}

__global__ __launch_bounds__(256)
void dist_kernel(const float* __restrict__ gw_real, const float* __restrict__ gw_imag,
                 const float* __restrict__ codebook, const int* __restrict__ prev,
                 const float* __restrict__ adj, const float* __restrict__ znorm,
                 const float* __restrict__ cnorm,
                 float* __restrict__ ws_min, int* __restrict__ ws_idx) {
  __shared__ float As[16][64];
  __shared__ float Bs[16][64];
  __shared__ int prevs[64];
  const int bm = blockIdx.x, bn = blockIdx.y;
  const int row0 = bm * 64, col0 = bn * 64;
  const int tid = threadIdx.x;
  const int tx = tid & 15, ty = tid >> 4;
  if (tid < 64) prevs[tid] = prev[row0 + tid];
  const int lm = tid >> 2;
  const int lk = (tid & 3) << 2;
  const int arow = row0 + lm;
  const int brow = col0 + lm;
  float acc[4][4] = {{0.f,0.f,0.f,0.f},{0.f,0.f,0.f,0.f},{0.f,0.f,0.f,0.f},{0.f,0.f,0.f,0.f}};
  for (int kk = 0; kk < DDIM; kk += 16) {
    const int k = kk + lk;
    float4 a, b;
    if (k < LDIM) a = *reinterpret_cast<const float4*>(gw_real + (size_t)arow * LDIM + k);
    else          a = *reinterpret_cast<const float4*>(gw_imag + (size_t)arow * LDIM + (k - LDIM));
    b = *reinterpret_cast<const float4*>(codebook + (size_t)brow * DDIM + k);
    __syncthreads();
    As[lk+0][lm]=a.x; As[lk+1][lm]=a.y; As[lk+2][lm]=a.z; As[lk+3][lm]=a.w;
    Bs[lk+0][lm]=b.x; Bs[lk+1][lm]=b.y; Bs[lk+2][lm]=b.z; Bs[lk+3][lm]=b.w;
    __syncthreads();
#pragma unroll
    for (int k2 = 0; k2 < 16; ++k2) {
      const float4 a4 = *reinterpret_cast<const float4*>(&As[k2][ty << 2]);
      const float4 b4 = *reinterpret_cast<const float4*>(&Bs[k2][tx << 2]);
      const float av[4] = {a4.x, a4.y, a4.z, a4.w};
      const float bv[4] = {b4.x, b4.y, b4.z, b4.w};
#pragma unroll
      for (int i = 0; i < 4; ++i)
#pragma unroll
        for (int j = 0; j < 4; ++j)
          acc[i][j] = fmaf(av[i], bv[j], acc[i][j]);
    }
  }
  const float4 cn4 = *reinterpret_cast<const float4*>(cnorm + col0 + (tx << 2));
  const float cnv[4] = {cn4.x, cn4.y, cn4.z, cn4.w};
#pragma unroll
  for (int i = 0; i < 4; ++i) {
    const int rsub = (ty << 2) + i;
    const int row = row0 + rsub;
    const float zn = znorm[row];
    const int p = prevs[rsub];
    const float4 ad4 = *reinterpret_cast<const float4*>(adj + (size_t)p * NDIM + col0 + (tx << 2));
    const float adv[4] = {ad4.x, ad4.y, ad4.z, ad4.w};
    float bv = FLT_BIG;
    int bi = -1;
#pragma unroll
    for (int j = 0; j < 4; ++j) {
      const float bias = 0.8f * (1.0f / (1.0f + expf(-adv[j])));
      const float dv = (zn + cnv[j]) - 2.0f * acc[i][j] - bias;
      const int col = col0 + (tx << 2) + j;
      if (dv < bv) { bv = dv; bi = col; }
    }
    for (int m = 1; m < 16; m <<= 1) {
      const float ov = __shfl_xor(bv, m, 64);
      const int   oi = __shfl_xor(bi, m, 64);
      if (ov < bv || (ov == bv && oi < bi)) { bv = ov; bi = oi; }
    }
    if (tx == 0) {
      ws_min[(size_t)row * 128 + bn] = bv;
      ws_idx[(size_t)row * 128 + bn] = bi;
    }
  }
}

__global__ __launch_bounds__(128)
void argmin_reduce(const float* __restrict__ ws_min, const int* __restrict__ ws_idx,
                   float* __restrict__ out, float* __restrict__ minfinal,
                   int* __restrict__ idxfinal) {
  const int row = blockIdx.x;
  const int t = threadIdx.x;
  __shared__ float sv[128];
  __shared__ int   si[128];
  sv[t] = ws_min[(size_t)row * 128 + t];
  si[t] = ws_idx[(size_t)row * 128 + t];
  __syncthreads();
  for (int s = 64; s > 0; s >>= 1) {
    if (t < s) {
      const float ov = sv[t + s];
      const int   oi = si[t + s];
      if (ov < sv[t] || (ov == sv[t] && oi < si[t])) { sv[t] = ov; si[t] = oi; }
    }
    __syncthreads();
  }
  if (t == 0) {
    out[OFF_IDX + row] = (float)si[0];
    minfinal[row] = sv[0];
    idxfinal[row] = si[0];
  }
}

__global__ __launch_bounds__(256)
void epilogue_kernel(const float* __restrict__ gw_real, const float* __restrict__ gw_imag,
                     const float* __restrict__ codebook,
                     const float* __restrict__ sal_w, const float* __restrict__ sal_b,
                     const float* __restrict__ conf_w, const float* __restrict__ conf_b,
                     const float* __restrict__ minfinal, const int* __restrict__ idxfinal,
                     float* __restrict__ out, float* __restrict__ rowloss) {
  __shared__ float s1[4], s2[4], s3[4];
  const int row = blockIdx.x;
  const int t = threadIdx.x;
  const int w = t >> 6, l = t & 63;
  const int k = t << 2;
  const int idx = idxfinal[row];
  const float4 qv = *reinterpret_cast<const float4*>(codebook + (size_t)idx * DDIM + k);
  float4 z;
  if (k < LDIM) z = *reinterpret_cast<const float4*>(gw_real + (size_t)row * LDIM + k);
  else          z = *reinterpret_cast<const float4*>(gw_imag + (size_t)row * LDIM + (k - LDIM));
  const float dx = qv.x - z.x, dy = qv.y - z.y, dz = qv.z - z.z, dw = qv.w - z.w;
  float4 st;
  st.x = z.x + dx; st.y = z.y + dy; st.z = z.z + dz; st.w = z.w + dw;
  float* dst = (k < LDIM) ? (out + OFF_REAL + (size_t)row * LDIM + k)
                          : (out + OFF_IMAG + (size_t)row * LDIM + (k - LDIM));
  *reinterpret_cast<float4*>(dst) = st;
  const float4 sw = *reinterpret_cast<const float4*>(sal_w + k);
  const float4 cw = *reinterpret_cast<const float4*>(conf_w + k);
  float r1 = st.x*sw.x + st.y*sw.y + st.z*sw.z + st.w*sw.w;
  float r2 = st.x*cw.x + st.y*cw.y + st.z*cw.z + st.w*cw.w;
  float r3 = dx*dx + dy*dy + dz*dz + dw*dw;
#pragma unroll
  for (int m = 1; m < 64; m <<= 1) {
    r1 += __shfl_xor(r1, m, 64);
    r2 += __shfl_xor(r2, m, 64);
    r3 += __shfl_xor(r3, m, 64);
  }
  if (l == 0) { s1[w] = r1; s2[w] = r2; s3[w] = r3; }
  __syncthreads();
  if (t == 0) {
    const float t1 = s1[0] + s1[1] + s1[2] + s1[3];
    const float t2 = s2[0] + s2[1] + s2[2] + s2[3];
    const float t3 = s3[0] + s3[1] + s3[2] + s3[3];
    out[OFF_SAL + row]  = t1 + sal_b[0] + 0.1f * (-minfinal[row]);
    out[OFF_CONF + row] = 1.0f / (1.0f + expf(-(t2 + conf_b[0])));
    rowloss[row] = t3;
  }
}

// ============ HOST ============

extern "C" void kernel_launch(void* const* d_in, const int* in_sizes, int n_in,
                              void* d_out, int out_size, void* d_ws, size_t ws_size,
                              hipStream_t stream) {
  const float* gw_real  = (const float*)d_in[0];
  const float* gw_imag  = (const float*)d_in[1];
  const int*   prev     = (const int*)d_in[2];
  const float* codebook = (const float*)d_in[3];
  const float* adj      = (const float*)d_in[4];
  const float* sal_w    = (const float*)d_in[5];
  const float* sal_b    = (const float*)d_in[6];
  const float* conf_w   = (const float*)d_in[7];
  const float* conf_b   = (const float*)d_in[8];
  float* out = (float*)d_out;
  char* ws = (char*)d_ws;

  const size_t matsz  = (size_t)RDIM * DDIM;             // bf16 elements per matrix
  const size_t nslice = (size_t)RDIM * 128;              // (row, 64-col-slice) cells
  size_t need = 2 * matsz * 2                            // zh, ch (bf16)
              + nslice * 4 + nslice * 8                  // keys, masks
              + 5 * (size_t)RDIM * 4 + 4096;             // znorm,cnorm,rowloss,spare

  if (ws_size >= need) {
    unsigned short* zh = (unsigned short*)ws;
    unsigned short* chh = zh + matsz;
    unsigned* keys = (unsigned*)(chh + matsz);
    unsigned long long* masks = (unsigned long long*)(keys + nslice);
    float* znorm    = (float*)(masks + nslice);
    float* cnorm    = znorm + RDIM;
    float* rowloss  = cnorm + NDIM;

    split_norms_kernel<<<(RDIM + NDIM) / 4, 256, 0, stream>>>(gw_real, gw_imag, codebook,
                                                              zh, chh, znorm, cnorm);
    dist_mfma_kernel<<<1024, 512, 0, stream>>>(zh, chh, cnorm, keys, masks);
    tail_kernel<<<RDIM, 256, 0, stream>>>(keys, masks, prev, adj, gw_real, gw_imag, codebook,
                                          sal_w, sal_b, conf_w, conf_b, znorm, cnorm,
                                          out, rowloss);
    loss_kernel<<<1, 256, 0, stream>>>(rowloss, out);
  } else {
    float* ws_min   = (float*)ws;
    int*   ws_idx   = (int*)(ws + (size_t)RDIM * 128 * 4);
    float* znorm    = (float*)(ws + (size_t)RDIM * 128 * 8);
    float* cnorm    = znorm + RDIM;
    float* minfinal = cnorm + NDIM;
    int*   idxfinal = (int*)(minfinal + RDIM);
    float* rowloss  = (float*)(idxfinal + RDIM);

    norms_kernel<<<RDIM + NDIM, 256, 0, stream>>>(gw_real, gw_imag, codebook, znorm, cnorm);
    dist_kernel<<<dim3(RDIM / 64, NDIM / 64), 256, 0, stream>>>(
        gw_real, gw_imag, codebook, prev, adj, znorm, cnorm, ws_min, ws_idx);
    argmin_reduce<<<RDIM, 128, 0, stream>>>(ws_min, ws_idx, out, minfinal, idxfinal);
    epilogue_kernel<<<RDIM, 256, 0, stream>>>(gw_real, gw_imag, codebook, sal_w, sal_b,
                                              conf_w, conf_b, minfinal, idxfinal, out, rowloss);
    loss_kernel<<<1, 256, 0, stream>>>(rowloss, out);
  }
}